// Round 5
// baseline (6981.644 us; speedup 1.0000x reference)
//
#include <hip/hip_runtime.h>

#define NN 50000
#define HH 256
#define EE 500000
#define EPSB 1e-5f

__device__ __forceinline__ float4 ld4(const float* p) { return *(const float4*)p; }

__device__ __forceinline__ float getc(const float4& v, int kk) {
  return kk == 0 ? v.x : kk == 1 ? v.y : kk == 2 ? v.z : v.w;
}

__device__ __forceinline__ unsigned short f2bf(float f) {
  unsigned int u = __float_as_uint(f);
  unsigned int r = (u + 0x7FFFu + ((u >> 16) & 1u)) >> 16;
  return (unsigned short)r;
}
__device__ __forceinline__ float bf2f(unsigned short s) {
  return __uint_as_float(((unsigned int)s) << 16);
}
__device__ __forceinline__ float bflo(unsigned int u) { return __uint_as_float(u << 16); }
__device__ __forceinline__ float bfhi(unsigned int u) { return __uint_as_float(u & 0xFFFF0000u); }

// ---------------- degree / normalization ----------------
__global__ void k_cnt_init(int* __restrict__ cnt) {
  int i = blockIdx.x * 256 + threadIdx.x;
  if (i < NN) cnt[i] = 1;  // self-loop
}
__global__ void k_cnt(const int* __restrict__ dst, int* __restrict__ cnt) {
  int e = blockIdx.x * 256 + threadIdx.x;
  if (e < EE) atomicAdd(&cnt[dst[e]], 1);
}
__global__ void k_dis(const int* __restrict__ cnt, float* __restrict__ dis) {
  int i = blockIdx.x * 256 + threadIdx.x;
  if (i < NN) dis[i] = rsqrtf((float)cnt[i]);
}

// ---------------- generic fp32 GEMM: C[M,Nn] = A[M,K] @ B[K,Nn] ----------------
__global__ __launch_bounds__(256, 2) void k_gemm(const float* __restrict__ A,
                                                 const float* __restrict__ B,
                                                 float* __restrict__ C,
                                                 int M, int K, int Nn) {
  __shared__ float As[128][36];
  const int t = threadIdx.x;
  const int ty = t >> 4, tx = t & 15;
  const int bm = blockIdx.x * 128, bn = blockIdx.y * 128;
  float acc[8][8] = {};
  for (int kc = 0; kc < K; kc += 32) {
#pragma unroll
    for (int q = 0; q < 4; ++q) {
      int idx = t + q * 256;
      int m = idx >> 3, kq = (idx & 7) * 4;
      float4 v = make_float4(0.f, 0.f, 0.f, 0.f);
      if (bm + m < M) v = ld4(&A[(size_t)(bm + m) * K + kc + kq]);
      *(float4*)&As[m][kq] = v;
    }
    __syncthreads();
#pragma unroll
    for (int k4 = 0; k4 < 8; ++k4) {
      float4 av[8];
#pragma unroll
      for (int i = 0; i < 8; ++i) av[i] = *(const float4*)&As[ty * 8 + i][k4 * 4];
#pragma unroll
      for (int kk = 0; kk < 4; ++kk) {
        int kg = kc + k4 * 4 + kk;
        float4 b0 = ld4(&B[(size_t)kg * Nn + bn + tx * 8]);
        float4 bh = ld4(&B[(size_t)kg * Nn + bn + tx * 8 + 4]);
#pragma unroll
        for (int i = 0; i < 8; ++i) {
          float a = getc(av[i], kk);
          acc[i][0] += a * b0.x; acc[i][1] += a * b0.y;
          acc[i][2] += a * b0.z; acc[i][3] += a * b0.w;
          acc[i][4] += a * bh.x; acc[i][5] += a * bh.y;
          acc[i][6] += a * bh.z; acc[i][7] += a * bh.w;
        }
      }
    }
    __syncthreads();
  }
#pragma unroll
  for (int i = 0; i < 8; ++i) {
    int r = bm + ty * 8 + i;
    if (r < M) {
      *(float4*)&C[(size_t)r * Nn + bn + tx * 8] =
          make_float4(acc[i][0], acc[i][1], acc[i][2], acc[i][3]);
      *(float4*)&C[(size_t)r * Nn + bn + tx * 8 + 4] =
          make_float4(acc[i][4], acc[i][5], acc[i][6], acc[i][7]);
    }
  }
}

// ---------------- same GEMM, bf16 output (for P|Q) ----------------
__global__ __launch_bounds__(256, 2) void k_gemm_bf16(const float* __restrict__ A,
                                                      const float* __restrict__ B,
                                                      unsigned short* __restrict__ C,
                                                      int M, int K, int Nn) {
  __shared__ float As[128][36];
  const int t = threadIdx.x;
  const int ty = t >> 4, tx = t & 15;
  const int bm = blockIdx.x * 128, bn = blockIdx.y * 128;
  float acc[8][8] = {};
  for (int kc = 0; kc < K; kc += 32) {
#pragma unroll
    for (int q = 0; q < 4; ++q) {
      int idx = t + q * 256;
      int m = idx >> 3, kq = (idx & 7) * 4;
      float4 v = make_float4(0.f, 0.f, 0.f, 0.f);
      if (bm + m < M) v = ld4(&A[(size_t)(bm + m) * K + kc + kq]);
      *(float4*)&As[m][kq] = v;
    }
    __syncthreads();
#pragma unroll
    for (int k4 = 0; k4 < 8; ++k4) {
      float4 av[8];
#pragma unroll
      for (int i = 0; i < 8; ++i) av[i] = *(const float4*)&As[ty * 8 + i][k4 * 4];
#pragma unroll
      for (int kk = 0; kk < 4; ++kk) {
        int kg = kc + k4 * 4 + kk;
        float4 b0 = ld4(&B[(size_t)kg * Nn + bn + tx * 8]);
        float4 bh = ld4(&B[(size_t)kg * Nn + bn + tx * 8 + 4]);
#pragma unroll
        for (int i = 0; i < 8; ++i) {
          float a = getc(av[i], kk);
          acc[i][0] += a * b0.x; acc[i][1] += a * b0.y;
          acc[i][2] += a * b0.z; acc[i][3] += a * b0.w;
          acc[i][4] += a * bh.x; acc[i][5] += a * bh.y;
          acc[i][6] += a * bh.z; acc[i][7] += a * bh.w;
        }
      }
    }
    __syncthreads();
  }
#pragma unroll
  for (int i = 0; i < 8; ++i) {
    int r = bm + ty * 8 + i;
    if (r < M) {
      unsigned int w0 = (unsigned int)f2bf(acc[i][0]) | ((unsigned int)f2bf(acc[i][1]) << 16);
      unsigned int w1 = (unsigned int)f2bf(acc[i][2]) | ((unsigned int)f2bf(acc[i][3]) << 16);
      unsigned int w2 = (unsigned int)f2bf(acc[i][4]) | ((unsigned int)f2bf(acc[i][5]) << 16);
      unsigned int w3 = (unsigned int)f2bf(acc[i][6]) | ((unsigned int)f2bf(acc[i][7]) << 16);
      *(uint4*)&C[(size_t)r * Nn + bn + tx * 8] = make_uint4(w0, w1, w2, w3);
    }
  }
}

// ---------------- GCN aggregation ----------------
__global__ void k_selfinit(const float* __restrict__ xw, const float* __restrict__ dis,
                           float* __restrict__ x) {
  int i = blockIdx.x * 256 + threadIdx.x;  // float4 index
  if (i < NN * 64) {
    int v = i >> 6;
    float c = dis[v] * dis[v];
    float4 wv = ld4(&xw[(size_t)i * 4]);
    float4 r = make_float4(wv.x * c, wv.y * c, wv.z * c, wv.w * c);
    *(float4*)&x[(size_t)i * 4] = r;
  }
}
__global__ void k_scatter(const int* __restrict__ ei, const float* __restrict__ xw,
                          const float* __restrict__ dis, float* __restrict__ x) {
  int gid = blockIdx.x * 256 + threadIdx.x;
  int e = gid >> 6;
  if (e >= EE) return;
  int c4 = (gid & 63) * 4;
  int s = ei[e], d = ei[EE + e];
  float cf = dis[s] * dis[d];
  float4 v = ld4(&xw[(size_t)s * 256 + c4]);
  float* xp = &x[(size_t)d * 256 + c4];
  atomicAdd(xp + 0, v.x * cf);
  atomicAdd(xp + 1, v.y * cf);
  atomicAdd(xp + 2, v.z * cf);
  atomicAdd(xp + 3, v.w * cf);
}

// ---------------- BatchNorm (training-mode) + ReLU ----------------
__global__ void k_bn_zero(float* __restrict__ s) {
  int i = blockIdx.x * 256 + threadIdx.x;
  if (i < 512) s[i] = 0.f;
}
__global__ void k_bn_stat(const float* __restrict__ x, float* __restrict__ sums) {
  int c = threadIdx.x;
  float s = 0.f, s2 = 0.f;
  for (int r = blockIdx.x; r < NN; r += gridDim.x) {
    float v = x[(size_t)r * HH + c];
    s += v; s2 += v * v;
  }
  atomicAdd(&sums[c], s);
  atomicAdd(&sums[HH + c], s2);
}
__global__ void k_bn_final(const float* __restrict__ sums, const float* __restrict__ gamma,
                           const float* __restrict__ beta, float* __restrict__ ss) {
  int c = threadIdx.x;
  float mu = sums[c] * (1.0f / NN);
  float var = sums[HH + c] * (1.0f / NN) - mu * mu;
  float s = gamma[c] * rsqrtf(var + EPSB);
  ss[c] = s;
  ss[HH + c] = beta[c] - mu * s;
}
__global__ void k_bn_apply(float* __restrict__ x, const float* __restrict__ ss) {
  int i = blockIdx.x * 256 + threadIdx.x;  // float4 index
  if (i < NN * 64) {
    int c4 = (i & 63) * 4;
    float4 sc = ld4(&ss[c4]);
    float4 sh = ld4(&ss[HH + c4]);
    float4 v = ld4(&x[(size_t)i * 4]);
    v.x = fmaxf(v.x * sc.x + sh.x, 0.f);
    v.y = fmaxf(v.y * sc.y + sh.y, 0.f);
    v.z = fmaxf(v.z * sc.z + sh.z, 0.f);
    v.w = fmaxf(v.w * sc.w + sh.w, 0.f);
    *(float4*)&x[(size_t)i * 4] = v;
  }
}

// ---------------- repack W1 -> [256][1024]: cols 0..511 = P-weights, 512.. = Q-weights
__global__ void k_w1repack(const float* __restrict__ W1, float* __restrict__ w1r) {
  int idx = blockIdx.x * 256 + threadIdx.x;
  if (idx < 256 * 1024) {
    int k = idx >> 10, j = idx & 1023;
    w1r[idx] = (j < 512) ? W1[k * 512 + j] : W1[(256 + k) * 512 + (j - 512)];
  }
}

// ---------------- fused edge MLP: 64 edges per block; pq in bf16 ----------------
__global__ __launch_bounds__(256, 2) void k_edge(
    const int* __restrict__ ei, const unsigned short* __restrict__ pq,
    const float* __restrict__ b1, const float* __restrict__ W2,
    const float* __restrict__ b2, const float* __restrict__ W3,
    const float* __restrict__ b3, const float* __restrict__ W4,
    const float* __restrict__ b4, float* __restrict__ out) {
  __shared__ int es[64], ed[64];
  __shared__ float h1[64][36];
  __shared__ unsigned short h2[64][264];
  __shared__ float red[64][17];
  const int t = threadIdx.x;
  const int e0 = blockIdx.x * 64;
  if (t < 64) {
    int e = e0 + t;
    es[t] = (e < EE) ? ei[e] : 0;
    ed[t] = (e < EE) ? ei[EE + e] : 0;
  }
  __syncthreads();

  // ---- gemm2: [64 x 512] @ W2[512 x 256]
  const int ty = t >> 5, tx = t & 31;  // rows ty*8.., cols tx*8..
  float acc2[8][8] = {};
  for (int kc = 0; kc < 512; kc += 32) {
    {  // h1 chunk build: each thread handles 8 bf16 of P and Q for one edge
      int e = t >> 2, kq = (t & 3) * 8;
      uint4 pu = *(const uint4*)&pq[(size_t)es[e] * 1024 + kc + kq];
      uint4 qu = *(const uint4*)&pq[(size_t)ed[e] * 1024 + 512 + kc + kq];
      float4 bb0 = ld4(&b1[kc + kq]);
      float4 bb1 = ld4(&b1[kc + kq + 4]);
      float4 h0, h4;
      h0.x = fmaxf(bflo(pu.x) + bflo(qu.x) + bb0.x, 0.f);
      h0.y = fmaxf(bfhi(pu.x) + bfhi(qu.x) + bb0.y, 0.f);
      h0.z = fmaxf(bflo(pu.y) + bflo(qu.y) + bb0.z, 0.f);
      h0.w = fmaxf(bfhi(pu.y) + bfhi(qu.y) + bb0.w, 0.f);
      h4.x = fmaxf(bflo(pu.z) + bflo(qu.z) + bb1.x, 0.f);
      h4.y = fmaxf(bfhi(pu.z) + bfhi(qu.z) + bb1.y, 0.f);
      h4.z = fmaxf(bflo(pu.w) + bflo(qu.w) + bb1.z, 0.f);
      h4.w = fmaxf(bfhi(pu.w) + bfhi(qu.w) + bb1.w, 0.f);
      *(float4*)&h1[e][kq] = h0;
      *(float4*)&h1[e][kq + 4] = h4;
    }
    __syncthreads();
#pragma unroll
    for (int k4 = 0; k4 < 8; ++k4) {
      float4 av[8];
#pragma unroll
      for (int i = 0; i < 8; ++i) av[i] = *(const float4*)&h1[ty * 8 + i][k4 * 4];
#pragma unroll
      for (int kk = 0; kk < 4; ++kk) {
        int kg = kc + k4 * 4 + kk;
        float4 b0 = ld4(&W2[kg * 256 + tx * 8]);
        float4 bh = ld4(&W2[kg * 256 + tx * 8 + 4]);
#pragma unroll
        for (int i = 0; i < 8; ++i) {
          float a = getc(av[i], kk);
          acc2[i][0] += a * b0.x; acc2[i][1] += a * b0.y;
          acc2[i][2] += a * b0.z; acc2[i][3] += a * b0.w;
          acc2[i][4] += a * bh.x; acc2[i][5] += a * bh.y;
          acc2[i][6] += a * bh.z; acc2[i][7] += a * bh.w;
        }
      }
    }
    __syncthreads();
  }
  // ---- h2 = bf16(relu(acc2 + b2))
  {
    float4 c0 = ld4(&b2[tx * 8]), c1 = ld4(&b2[tx * 8 + 4]);
    float bb[8] = {c0.x, c0.y, c0.z, c0.w, c1.x, c1.y, c1.z, c1.w};
#pragma unroll
    for (int i = 0; i < 8; ++i) {
      int r = ty * 8 + i;
      unsigned int w[4];
#pragma unroll
      for (int j = 0; j < 4; ++j) {
        unsigned short lo = f2bf(fmaxf(acc2[i][2 * j] + bb[2 * j], 0.f));
        unsigned short hi = f2bf(fmaxf(acc2[i][2 * j + 1] + bb[2 * j + 1], 0.f));
        w[j] = (unsigned int)lo | ((unsigned int)hi << 16);
      }
      *(uint4*)&h2[r][tx * 8] = make_uint4(w[0], w[1], w[2], w[3]);
    }
  }
  __syncthreads();

  // ---- gemm3: [64 x 256] @ W3[256 x 128]
  const int ty4 = t >> 4, tx4 = t & 15;  // rows ty4*4.., cols tx4*8..
  float acc3[4][8] = {};
  for (int k4 = 0; k4 < 64; ++k4) {
    float a3[4][4];
#pragma unroll
    for (int i = 0; i < 4; ++i) {
      ushort4 u = *(const ushort4*)&h2[ty4 * 4 + i][k4 * 4];
      a3[i][0] = bf2f(u.x); a3[i][1] = bf2f(u.y);
      a3[i][2] = bf2f(u.z); a3[i][3] = bf2f(u.w);
    }
#pragma unroll
    for (int kk = 0; kk < 4; ++kk) {
      int kg = k4 * 4 + kk;
      float4 b0 = ld4(&W3[kg * 128 + tx4 * 8]);
      float4 bh = ld4(&W3[kg * 128 + tx4 * 8 + 4]);
#pragma unroll
      for (int i = 0; i < 4; ++i) {
        float a = a3[i][kk];
        acc3[i][0] += a * b0.x; acc3[i][1] += a * b0.y;
        acc3[i][2] += a * b0.z; acc3[i][3] += a * b0.w;
        acc3[i][4] += a * bh.x; acc3[i][5] += a * bh.y;
        acc3[i][6] += a * bh.z; acc3[i][7] += a * bh.w;
      }
    }
  }
  // ---- h3 relu + dot with W4, block reduction
  {
    float4 w40 = ld4(&W4[tx4 * 8]), w41 = ld4(&W4[tx4 * 8 + 4]);
    float4 d30 = ld4(&b3[tx4 * 8]), d31 = ld4(&b3[tx4 * 8 + 4]);
    float wv[8] = {w40.x, w40.y, w40.z, w40.w, w41.x, w41.y, w41.z, w41.w};
    float bv[8] = {d30.x, d30.y, d30.z, d30.w, d31.x, d31.y, d31.z, d31.w};
#pragma unroll
    for (int i = 0; i < 4; ++i) {
      float s = 0.f;
#pragma unroll
      for (int j = 0; j < 8; ++j) s += fmaxf(acc3[i][j] + bv[j], 0.f) * wv[j];
      red[ty4 * 4 + i][tx4] = s;
    }
  }
  __syncthreads();
  if (t < 64) {
    float s = 0.f;
#pragma unroll
    for (int x = 0; x < 16; ++x) s += red[t][x];
    int e = e0 + t;
    if (e < EE) out[e] = s + b4[0];
  }
}

extern "C" void kernel_launch(void* const* d_in, const int* in_sizes, int n_in,
                              void* d_out, int out_size, void* d_ws, size_t ws_size,
                              hipStream_t stream) {
  const int* ei = (const int*)d_in[0];
  const float* node_emb = (const float*)d_in[1];
  const float* convW = (const float*)d_in[2];
  // d_in[3] = convB: per-channel constant cancels exactly in training-mode BN -> unused
  const float* bn_gamma = (const float*)d_in[4];
  const float* bn_beta = (const float*)d_in[5];
  const float* W1 = (const float*)d_in[6];
  const float* b1 = (const float*)d_in[7];
  const float* W2 = (const float*)d_in[8];
  const float* b2 = (const float*)d_in[9];
  const float* W3 = (const float*)d_in[10];
  const float* b3 = (const float*)d_in[11];
  const float* W4 = (const float*)d_in[12];
  const float* b4 = (const float*)d_in[13];
  float* out = (float*)d_out;

  // Workspace: 155,058,176 bytes total (halved from 309 MB; suspected ws overflow).
  // xw (fp32, layer-loop only) aliases the pqb (bf16) region — xw is dead before
  // pqb is first written.
  char* w = (char*)d_ws;
  float* x_buf = (float*)w;             w += 51200000;   // [50000][256] fp32
  char* uni = w;                        w += 102400000;  // union region
  float* xw = (float*)uni;                               // [50000][256] fp32 (layers)
  unsigned short* pqb = (unsigned short*)uni;            // [50000][1024] bf16 (P|Q)
  float* w1r   = (float*)w; w += 1048576;    // [256][1024]
  float* dis   = (float*)w; w += 200704;     // [50000]
  int*   cnt   = (int*)w;   w += 200704;     // [50000]
  float* bnsum = (float*)w; w += 4096;       // [512]
  float* bnss  = (float*)w; w += 4096;       // [512] scale|shift
  (void)ws_size; (void)in_sizes; (void)n_in; (void)out_size;

  k_cnt_init<<<196, 256, 0, stream>>>(cnt);
  k_cnt<<<(EE + 255) / 256, 256, 0, stream>>>(ei + EE, cnt);
  k_dis<<<196, 256, 0, stream>>>(cnt, dis);

  for (int l = 0; l < 2; ++l) {
    const float* A = (l == 0) ? node_emb : x_buf;
    k_gemm<<<dim3(391, 2), 256, 0, stream>>>(A, convW + l * HH * HH, xw, NN, HH, HH);
    k_selfinit<<<12500, 256, 0, stream>>>(xw, dis, x_buf);
    k_scatter<<<125000, 256, 0, stream>>>(ei, xw, dis, x_buf);
    k_bn_zero<<<2, 256, 0, stream>>>(bnsum);
    k_bn_stat<<<512, 256, 0, stream>>>(x_buf, bnsum);
    k_bn_final<<<1, 256, 0, stream>>>(bnsum, bn_gamma + l * HH, bn_beta + l * HH, bnss);
    k_bn_apply<<<12500, 256, 0, stream>>>(x_buf, bnss);
  }

  k_w1repack<<<1024, 256, 0, stream>>>(W1, w1r);
  k_gemm_bf16<<<dim3(391, 8), 256, 0, stream>>>(x_buf, w1r, pqb, NN, HH, 1024);
  k_edge<<<7813, 256, 0, stream>>>(ei, pqb, b1, W2, b2, W3, b3, W4, b4, out);
}

// Round 6
// 4801.957 us; speedup vs baseline: 1.4539x; 1.4539x over previous
//
#include <hip/hip_runtime.h>

#define NN 50000
#define HH 256
#define EE 500000
#define EPSB 1e-5f

typedef __attribute__((ext_vector_type(8))) short s8v;   // 8 bf16 (4 VGPR)
typedef __attribute__((ext_vector_type(4))) float f4v;   // MFMA acc

__device__ __forceinline__ float4 ld4(const float* p) { return *(const float4*)p; }

__device__ __forceinline__ float getc(const float4& v, int kk) {
  return kk == 0 ? v.x : kk == 1 ? v.y : kk == 2 ? v.z : v.w;
}

__device__ __forceinline__ unsigned short f2bf(float f) {
  unsigned int u = __float_as_uint(f);
  unsigned int r = (u + 0x7FFFu + ((u >> 16) & 1u)) >> 16;
  return (unsigned short)r;
}
__device__ __forceinline__ float bf2f(unsigned short s) {
  return __uint_as_float(((unsigned int)s) << 16);
}
__device__ __forceinline__ float bflo(unsigned int u) { return __uint_as_float(u << 16); }
__device__ __forceinline__ float bfhi(unsigned int u) { return __uint_as_float(u & 0xFFFF0000u); }
// relu + pack 2 bf16
__device__ __forceinline__ unsigned int pk2(float a, float b) {
  return (unsigned int)f2bf(fmaxf(a, 0.f)) | ((unsigned int)f2bf(fmaxf(b, 0.f)) << 16);
}

// ---------------- degree / normalization ----------------
__global__ void k_cnt_init(int* __restrict__ cnt) {
  int i = blockIdx.x * 256 + threadIdx.x;
  if (i < NN) cnt[i] = 1;  // self-loop
}
__global__ void k_cnt(const int* __restrict__ dst, int* __restrict__ cnt) {
  int e = blockIdx.x * 256 + threadIdx.x;
  if (e < EE) atomicAdd(&cnt[dst[e]], 1);
}
__global__ void k_dis(const int* __restrict__ cnt, float* __restrict__ dis) {
  int i = blockIdx.x * 256 + threadIdx.x;
  if (i < NN) dis[i] = rsqrtf((float)cnt[i]);
}

// ---------------- generic fp32 GEMM: C[M,Nn] = A[M,K] @ B[K,Nn] ----------------
__global__ __launch_bounds__(256, 2) void k_gemm(const float* __restrict__ A,
                                                 const float* __restrict__ B,
                                                 float* __restrict__ C,
                                                 int M, int K, int Nn) {
  __shared__ float As[128][36];
  const int t = threadIdx.x;
  const int ty = t >> 4, tx = t & 15;
  const int bm = blockIdx.x * 128, bn = blockIdx.y * 128;
  float acc[8][8] = {};
  for (int kc = 0; kc < K; kc += 32) {
#pragma unroll
    for (int q = 0; q < 4; ++q) {
      int idx = t + q * 256;
      int m = idx >> 3, kq = (idx & 7) * 4;
      float4 v = make_float4(0.f, 0.f, 0.f, 0.f);
      if (bm + m < M) v = ld4(&A[(size_t)(bm + m) * K + kc + kq]);
      *(float4*)&As[m][kq] = v;
    }
    __syncthreads();
#pragma unroll
    for (int k4 = 0; k4 < 8; ++k4) {
      float4 av[8];
#pragma unroll
      for (int i = 0; i < 8; ++i) av[i] = *(const float4*)&As[ty * 8 + i][k4 * 4];
#pragma unroll
      for (int kk = 0; kk < 4; ++kk) {
        int kg = kc + k4 * 4 + kk;
        float4 b0 = ld4(&B[(size_t)kg * Nn + bn + tx * 8]);
        float4 bh = ld4(&B[(size_t)kg * Nn + bn + tx * 8 + 4]);
#pragma unroll
        for (int i = 0; i < 8; ++i) {
          float a = getc(av[i], kk);
          acc[i][0] += a * b0.x; acc[i][1] += a * b0.y;
          acc[i][2] += a * b0.z; acc[i][3] += a * b0.w;
          acc[i][4] += a * bh.x; acc[i][5] += a * bh.y;
          acc[i][6] += a * bh.z; acc[i][7] += a * bh.w;
        }
      }
    }
    __syncthreads();
  }
#pragma unroll
  for (int i = 0; i < 8; ++i) {
    int r = bm + ty * 8 + i;
    if (r < M) {
      *(float4*)&C[(size_t)r * Nn + bn + tx * 8] =
          make_float4(acc[i][0], acc[i][1], acc[i][2], acc[i][3]);
      *(float4*)&C[(size_t)r * Nn + bn + tx * 8 + 4] =
          make_float4(acc[i][4], acc[i][5], acc[i][6], acc[i][7]);
    }
  }
}

// ---------------- same GEMM, bf16 output (for P|Q) ----------------
__global__ __launch_bounds__(256, 2) void k_gemm_bf16(const float* __restrict__ A,
                                                      const float* __restrict__ B,
                                                      unsigned short* __restrict__ C,
                                                      int M, int K, int Nn) {
  __shared__ float As[128][36];
  const int t = threadIdx.x;
  const int ty = t >> 4, tx = t & 15;
  const int bm = blockIdx.x * 128, bn = blockIdx.y * 128;
  float acc[8][8] = {};
  for (int kc = 0; kc < K; kc += 32) {
#pragma unroll
    for (int q = 0; q < 4; ++q) {
      int idx = t + q * 256;
      int m = idx >> 3, kq = (idx & 7) * 4;
      float4 v = make_float4(0.f, 0.f, 0.f, 0.f);
      if (bm + m < M) v = ld4(&A[(size_t)(bm + m) * K + kc + kq]);
      *(float4*)&As[m][kq] = v;
    }
    __syncthreads();
#pragma unroll
    for (int k4 = 0; k4 < 8; ++k4) {
      float4 av[8];
#pragma unroll
      for (int i = 0; i < 8; ++i) av[i] = *(const float4*)&As[ty * 8 + i][k4 * 4];
#pragma unroll
      for (int kk = 0; kk < 4; ++kk) {
        int kg = kc + k4 * 4 + kk;
        float4 b0 = ld4(&B[(size_t)kg * Nn + bn + tx * 8]);
        float4 bh = ld4(&B[(size_t)kg * Nn + bn + tx * 8 + 4]);
#pragma unroll
        for (int i = 0; i < 8; ++i) {
          float a = getc(av[i], kk);
          acc[i][0] += a * b0.x; acc[i][1] += a * b0.y;
          acc[i][2] += a * b0.z; acc[i][3] += a * b0.w;
          acc[i][4] += a * bh.x; acc[i][5] += a * bh.y;
          acc[i][6] += a * bh.z; acc[i][7] += a * bh.w;
        }
      }
    }
    __syncthreads();
  }
#pragma unroll
  for (int i = 0; i < 8; ++i) {
    int r = bm + ty * 8 + i;
    if (r < M) {
      unsigned int w0 = (unsigned int)f2bf(acc[i][0]) | ((unsigned int)f2bf(acc[i][1]) << 16);
      unsigned int w1 = (unsigned int)f2bf(acc[i][2]) | ((unsigned int)f2bf(acc[i][3]) << 16);
      unsigned int w2 = (unsigned int)f2bf(acc[i][4]) | ((unsigned int)f2bf(acc[i][5]) << 16);
      unsigned int w3 = (unsigned int)f2bf(acc[i][6]) | ((unsigned int)f2bf(acc[i][7]) << 16);
      *(uint4*)&C[(size_t)r * Nn + bn + tx * 8] = make_uint4(w0, w1, w2, w3);
    }
  }
}

// ---------------- GCN aggregation ----------------
__global__ void k_selfinit(const float* __restrict__ xw, const float* __restrict__ dis,
                           float* __restrict__ x) {
  int i = blockIdx.x * 256 + threadIdx.x;  // float4 index
  if (i < NN * 64) {
    int v = i >> 6;
    float c = dis[v] * dis[v];
    float4 wv = ld4(&xw[(size_t)i * 4]);
    float4 r = make_float4(wv.x * c, wv.y * c, wv.z * c, wv.w * c);
    *(float4*)&x[(size_t)i * 4] = r;
  }
}
__global__ void k_scatter(const int* __restrict__ ei, const float* __restrict__ xw,
                          const float* __restrict__ dis, float* __restrict__ x) {
  int gid = blockIdx.x * 256 + threadIdx.x;
  int e = gid >> 6;
  if (e >= EE) return;
  int c4 = (gid & 63) * 4;
  int s = ei[e], d = ei[EE + e];
  float cf = dis[s] * dis[d];
  float4 v = ld4(&xw[(size_t)s * 256 + c4]);
  float* xp = &x[(size_t)d * 256 + c4];
  atomicAdd(xp + 0, v.x * cf);
  atomicAdd(xp + 1, v.y * cf);
  atomicAdd(xp + 2, v.z * cf);
  atomicAdd(xp + 3, v.w * cf);
}

// ---------------- BatchNorm (training-mode) + ReLU ----------------
__global__ void k_bn_zero(float* __restrict__ s) {
  int i = blockIdx.x * 256 + threadIdx.x;
  if (i < 512) s[i] = 0.f;
}
__global__ void k_bn_stat(const float* __restrict__ x, float* __restrict__ sums) {
  int c = threadIdx.x;
  float s = 0.f, s2 = 0.f;
  for (int r = blockIdx.x; r < NN; r += gridDim.x) {
    float v = x[(size_t)r * HH + c];
    s += v; s2 += v * v;
  }
  atomicAdd(&sums[c], s);
  atomicAdd(&sums[HH + c], s2);
}
__global__ void k_bn_final(const float* __restrict__ sums, const float* __restrict__ gamma,
                           const float* __restrict__ beta, float* __restrict__ ss) {
  int c = threadIdx.x;
  float mu = sums[c] * (1.0f / NN);
  float var = sums[HH + c] * (1.0f / NN) - mu * mu;
  float s = gamma[c] * rsqrtf(var + EPSB);
  ss[c] = s;
  ss[HH + c] = beta[c] - mu * s;
}
__global__ void k_bn_apply(float* __restrict__ x, const float* __restrict__ ss) {
  int i = blockIdx.x * 256 + threadIdx.x;  // float4 index
  if (i < NN * 64) {
    int c4 = (i & 63) * 4;
    float4 sc = ld4(&ss[c4]);
    float4 sh = ld4(&ss[HH + c4]);
    float4 v = ld4(&x[(size_t)i * 4]);
    v.x = fmaxf(v.x * sc.x + sh.x, 0.f);
    v.y = fmaxf(v.y * sc.y + sh.y, 0.f);
    v.z = fmaxf(v.z * sc.z + sh.z, 0.f);
    v.w = fmaxf(v.w * sc.w + sh.w, 0.f);
    *(float4*)&x[(size_t)i * 4] = v;
  }
}

// ---------------- repack W1 -> [256][1024]: cols 0..511 = P-weights, 512.. = Q-weights
__global__ void k_w1repack(const float* __restrict__ W1, float* __restrict__ w1r) {
  int idx = blockIdx.x * 256 + threadIdx.x;
  if (idx < 256 * 1024) {
    int k = idx >> 10, j = idx & 1023;
    w1r[idx] = (j < 512) ? W1[k * 512 + j] : W1[(256 + k) * 512 + (j - 512)];
  }
}

// ---------------- weight -> MFMA-fragment-linear bf16 packs ----------------
// W2f: A-operand frags for gemm2 (n-rows x k). flat u = ((nt*16 + ksg)*64 + lane),
// 8 bf16 each: element = W2[(ksg*32 + (lane>>4)*8 + j)][nt*16 + (lane&15)].
__global__ void k_w2frag(const float* __restrict__ W2, unsigned short* __restrict__ W2f) {
  int u = blockIdx.x * 256 + threadIdx.x;  // [0, 16384)
  int lane = u & 63, ksg = (u >> 6) & 15, nt = u >> 10;
  int g = lane >> 4, li = lane & 15;
  unsigned int wd[4];
#pragma unroll
  for (int jj = 0; jj < 4; ++jj) {
    float a = W2[(size_t)(ksg * 32 + g * 8 + jj * 2) * 256 + nt * 16 + li];
    float b = W2[(size_t)(ksg * 32 + g * 8 + jj * 2 + 1) * 256 + nt * 16 + li];
    wd[jj] = (unsigned int)f2bf(a) | ((unsigned int)f2bf(b) << 16);
  }
  *(uint4*)&W2f[(size_t)u * 8] = make_uint4(wd[0], wd[1], wd[2], wd[3]);
}
// W3f: A-operand frags for gemm3 (m-rows x n). element = W3[(ks*32+(lane>>4)*8+j)][mt*16+(lane&15)]
__global__ void k_w3frag(const float* __restrict__ W3, unsigned short* __restrict__ W3f) {
  int u = blockIdx.x * 256 + threadIdx.x;  // [0, 4096)
  int lane = u & 63, ks = (u >> 6) & 7, mt = u >> 9;
  int g = lane >> 4, li = lane & 15;
  unsigned int wd[4];
#pragma unroll
  for (int jj = 0; jj < 4; ++jj) {
    float a = W3[(size_t)(ks * 32 + g * 8 + jj * 2) * 128 + mt * 16 + li];
    float b = W3[(size_t)(ks * 32 + g * 8 + jj * 2 + 1) * 128 + mt * 16 + li];
    wd[jj] = (unsigned int)f2bf(a) | ((unsigned int)f2bf(b) << 16);
  }
  *(uint4*)&W3f[(size_t)u * 8] = make_uint4(wd[0], wd[1], wd[2], wd[3]);
}

// ---------------- fused edge MLP, MFMA version: 64 edges / block ----------------
// Transposed chain: gemm2 D[n][e] = W2t x h1t, gemm3 D[m][e] = W3t x h2t.
// A-frag: row = lane&15, k = (lane>>4)*8+j (fragment-linear from W2f/W3f, coalesced).
// B-frag: col = lane&15 (edge), k contiguous from LDS (XOR-swizzled, G4).
// C/D: col = lane&15, row = (lane>>4)*4 + reg  [m89-verified].
__global__ __launch_bounds__(256, 2) void k_edge(
    const int* __restrict__ ei, const unsigned short* __restrict__ pq,
    const float* __restrict__ b1, const unsigned short* __restrict__ W2f,
    const float* __restrict__ b2, const unsigned short* __restrict__ W3f,
    const float* __restrict__ b3, const float* __restrict__ W4,
    const float* __restrict__ b4, float* __restrict__ out) {
  __shared__ uint4 h1q[2048];       // 32 KB: h1 half-tile [64 e][256 k] bf16, swizzled
  __shared__ uint4 h2q[2048];       // 32 KB: h2 [64 e][256 n] bf16, swizzled
  __shared__ float red[64][17];
  __shared__ int es[64], ed[64];
  char* h1b = (char*)h1q;
  char* h2b = (char*)h2q;
  const int t = threadIdx.x;
  const int e0 = blockIdx.x * 64;
  if (t < 64) {
    int e = e0 + t;
    es[t] = (e < EE) ? ei[e] : 0;
    ed[t] = (e < EE) ? ei[EE + e] : 0;
  }
  __syncthreads();

  const int w = t >> 6, l = t & 63, g = l >> 4, li = l & 15;

  f4v acc2[4][4];
#pragma unroll
  for (int a = 0; a < 4; ++a)
#pragma unroll
    for (int b = 0; b < 4; ++b)
#pragma unroll
      for (int r = 0; r < 4; ++r) acc2[a][b][r] = 0.f;

  // ---- gemm2: [256 n][64 e] += W2t[n][512] x h1t[512][e], two K-halves of 256
  for (int half = 0; half < 2; ++half) {
    {  // build h1 half: h1[e][kk] = relu(P[src][k] + Q[dst][k] + b1[k]), bf16
      int e = t >> 2, q = t & 3;
      size_t bp = (size_t)es[e] * 1024 + half * 256;
      size_t bq = (size_t)ed[e] * 1024 + 512 + half * 256;
      int sw = (e & 7) << 4;
#pragma unroll
      for (int j = 0; j < 8; ++j) {
        int kk = q * 64 + j * 8;
        uint4 pu = *(const uint4*)&pq[bp + kk];
        uint4 qu = *(const uint4*)&pq[bq + kk];
        float4 c0 = ld4(&b1[half * 256 + kk]);
        float4 c1 = ld4(&b1[half * 256 + kk + 4]);
        unsigned int r0 = pk2(bflo(pu.x) + bflo(qu.x) + c0.x, bfhi(pu.x) + bfhi(qu.x) + c0.y);
        unsigned int r1 = pk2(bflo(pu.y) + bflo(qu.y) + c0.z, bfhi(pu.y) + bfhi(qu.y) + c0.w);
        unsigned int r2 = pk2(bflo(pu.z) + bflo(qu.z) + c1.x, bfhi(pu.z) + bfhi(qu.z) + c1.y);
        unsigned int r3 = pk2(bflo(pu.w) + bflo(qu.w) + c1.z, bfhi(pu.w) + bfhi(qu.w) + c1.w);
        *(uint4*)(h1b + ((e * 512 + kk * 2) ^ sw)) = make_uint4(r0, r1, r2, r3);
      }
    }
    __syncthreads();
#pragma unroll
    for (int ks = 0; ks < 8; ++ks) {
      s8v af[4], bf[4];
#pragma unroll
      for (int a = 0; a < 4; ++a)
        af[a] = *(const s8v*)&W2f[(size_t)(((w * 4 + a) * 16 + half * 8 + ks) * 64 + l) * 8];
#pragma unroll
      for (int b = 0; b < 4; ++b)
        bf[b] = *(const s8v*)(h1b + ((((b * 16 + li) * 512) + ks * 64 + g * 16) ^ ((li & 7) << 4)));
#pragma unroll
      for (int a = 0; a < 4; ++a)
#pragma unroll
        for (int b = 0; b < 4; ++b)
          acc2[a][b] = __builtin_amdgcn_mfma_f32_16x16x32_bf16(af[a], bf[b], acc2[a][b], 0, 0, 0);
    }
    __syncthreads();  // protect h1 overwrite / h2 write
  }

  // ---- h2[e][n] = bf16(relu(acc2 + b2[n])), swizzled by e
#pragma unroll
  for (int a = 0; a < 4; ++a) {
    int nb = w * 64 + a * 16 + g * 4;
    float4 bv = ld4(&b2[nb]);
#pragma unroll
    for (int b = 0; b < 4; ++b) {
      f4v v = acc2[a][b];
      uint2 pkd;
      pkd.x = pk2(v[0] + bv.x, v[1] + bv.y);
      pkd.y = pk2(v[2] + bv.z, v[3] + bv.w);
      *(uint2*)(h2b + ((((b * 16 + li) * 512) + nb * 2) ^ ((li & 7) << 4))) = pkd;
    }
  }
  __syncthreads();

  // ---- gemm3: [128 m][64 e] = W3t[m][256] x h2t[256][e]
  f4v acc3[2][4];
#pragma unroll
  for (int c = 0; c < 2; ++c)
#pragma unroll
    for (int b = 0; b < 4; ++b)
#pragma unroll
      for (int r = 0; r < 4; ++r) acc3[c][b][r] = 0.f;
#pragma unroll
  for (int ks = 0; ks < 8; ++ks) {
    s8v am[2], be[4];
#pragma unroll
    for (int c = 0; c < 2; ++c)
      am[c] = *(const s8v*)&W3f[(size_t)(((w * 2 + c) * 8 + ks) * 64 + l) * 8];
#pragma unroll
    for (int b = 0; b < 4; ++b)
      be[b] = *(const s8v*)(h2b + ((((b * 16 + li) * 512) + ks * 64 + g * 16) ^ ((li & 7) << 4)));
#pragma unroll
    for (int c = 0; c < 2; ++c)
#pragma unroll
      for (int b = 0; b < 4; ++b)
        acc3[c][b] = __builtin_amdgcn_mfma_f32_16x16x32_bf16(am[c], be[b], acc3[c][b], 0, 0, 0);
  }

  // ---- h3 relu + dot W4 -> red -> out
  float part[4] = {0.f, 0.f, 0.f, 0.f};
#pragma unroll
  for (int c = 0; c < 2; ++c) {
    int mb = (w * 2 + c) * 16 + g * 4;
    float4 b3v = ld4(&b3[mb]);
    float4 w4v = ld4(&W4[mb]);
#pragma unroll
    for (int b = 0; b < 4; ++b) {
      f4v v = acc3[c][b];
      part[b] += fmaxf(v[0] + b3v.x, 0.f) * w4v.x + fmaxf(v[1] + b3v.y, 0.f) * w4v.y +
                 fmaxf(v[2] + b3v.z, 0.f) * w4v.z + fmaxf(v[3] + b3v.w, 0.f) * w4v.w;
    }
  }
#pragma unroll
  for (int b = 0; b < 4; ++b) red[b * 16 + li][w * 4 + g] = part[b];
  __syncthreads();
  if (t < 64) {
    float s = 0.f;
#pragma unroll
    for (int x = 0; x < 16; ++x) s += red[t][x];
    int e = e0 + t;
    if (e < EE) out[e] = s + b4[0];
  }
}

extern "C" void kernel_launch(void* const* d_in, const int* in_sizes, int n_in,
                              void* d_out, int out_size, void* d_ws, size_t ws_size,
                              hipStream_t stream) {
  const int* ei = (const int*)d_in[0];
  const float* node_emb = (const float*)d_in[1];
  const float* convW = (const float*)d_in[2];
  // d_in[3] = convB: cancels exactly in training-mode BN -> unused
  const float* bn_gamma = (const float*)d_in[4];
  const float* bn_beta = (const float*)d_in[5];
  const float* W1 = (const float*)d_in[6];
  const float* b1 = (const float*)d_in[7];
  const float* W2 = (const float*)d_in[8];
  const float* b2 = (const float*)d_in[9];
  const float* W3 = (const float*)d_in[10];
  const float* b3 = (const float*)d_in[11];
  const float* W4 = (const float*)d_in[12];
  const float* b4 = (const float*)d_in[13];
  float* out = (float*)d_out;

  char* w = (char*)d_ws;
  float* x_buf = (float*)w;             w += 51200000;   // [50000][256] fp32
  char* uni = w;                        w += 102400000;  // union region
  float* xw = (float*)uni;                               // [50000][256] fp32 (layers)
  unsigned short* pqb = (unsigned short*)uni;            // [50000][1024] bf16 (P|Q)
  float* w1r   = (float*)w; w += 1048576;    // [256][1024]
  float* dis   = (float*)w; w += 200704;     // [50000]
  int*   cnt   = (int*)w;   w += 200704;     // [50000]
  float* bnsum = (float*)w; w += 4096;       // [512]
  float* bnss  = (float*)w; w += 4096;       // [512]
  unsigned short* W2f = (unsigned short*)w; w += 262144;  // frag-linear bf16 W2
  unsigned short* W3f = (unsigned short*)w; w += 65536;   // frag-linear bf16 W3
  (void)ws_size; (void)in_sizes; (void)n_in; (void)out_size;

  k_cnt_init<<<196, 256, 0, stream>>>(cnt);
  k_cnt<<<(EE + 255) / 256, 256, 0, stream>>>(ei + EE, cnt);
  k_dis<<<196, 256, 0, stream>>>(cnt, dis);
  k_w2frag<<<64, 256, 0, stream>>>(W2, W2f);
  k_w3frag<<<16, 256, 0, stream>>>(W3, W3f);

  for (int l = 0; l < 2; ++l) {
    const float* A = (l == 0) ? node_emb : x_buf;
    k_gemm<<<dim3(391, 2), 256, 0, stream>>>(A, convW + l * HH * HH, xw, NN, HH, HH);
    k_selfinit<<<12500, 256, 0, stream>>>(xw, dis, x_buf);
    k_scatter<<<125000, 256, 0, stream>>>(ei, xw, dis, x_buf);
    k_bn_zero<<<2, 256, 0, stream>>>(bnsum);
    k_bn_stat<<<512, 256, 0, stream>>>(x_buf, bnsum);
    k_bn_final<<<1, 256, 0, stream>>>(bnsum, bn_gamma + l * HH, bn_beta + l * HH, bnss);
    k_bn_apply<<<12500, 256, 0, stream>>>(x_buf, bnss);
  }

  k_w1repack<<<1024, 256, 0, stream>>>(W1, w1r);
  k_gemm_bf16<<<dim3(391, 8), 256, 0, stream>>>(x_buf, w1r, pqb, NN, HH, 1024);
  k_edge<<<7813, 256, 0, stream>>>(ei, pqb, b1, W2f, b2, W3f, b3, W4, b4, out);
}

// Round 7
// 1680.635 us; speedup vs baseline: 4.1542x; 2.8572x over previous
//
#include <hip/hip_runtime.h>

#define NN 50000
#define HH 256
#define EE 500000
#define EPSB 1e-5f

typedef __attribute__((ext_vector_type(8))) short s8v;   // 8 bf16 (4 VGPR)
typedef __attribute__((ext_vector_type(4))) float f4v;   // MFMA acc

__device__ __forceinline__ float4 ld4(const float* p) { return *(const float4*)p; }

__device__ __forceinline__ float getc(const float4& v, int kk) {
  return kk == 0 ? v.x : kk == 1 ? v.y : kk == 2 ? v.z : v.w;
}

__device__ __forceinline__ unsigned short f2bf(float f) {
  unsigned int u = __float_as_uint(f);
  unsigned int r = (u + 0x7FFFu + ((u >> 16) & 1u)) >> 16;
  return (unsigned short)r;
}
__device__ __forceinline__ float bf2f(unsigned short s) {
  return __uint_as_float(((unsigned int)s) << 16);
}
__device__ __forceinline__ float bflo(unsigned int u) { return __uint_as_float(u << 16); }
__device__ __forceinline__ float bfhi(unsigned int u) { return __uint_as_float(u & 0xFFFF0000u); }
__device__ __forceinline__ unsigned int pk2(float a, float b) {
  return (unsigned int)f2bf(fmaxf(a, 0.f)) | ((unsigned int)f2bf(fmaxf(b, 0.f)) << 16);
}

// ---------------- degree / CSR build ----------------
__global__ void k_cnt_init(int* __restrict__ cnt) {
  int i = blockIdx.x * 256 + threadIdx.x;
  if (i < NN) cnt[i] = 1;  // self-loop
}
__global__ void k_cnt(const int* __restrict__ dst, int* __restrict__ cnt) {
  int e = blockIdx.x * 256 + threadIdx.x;
  if (e < EE) atomicAdd(&cnt[dst[e]], 1);
}
__global__ void k_dis(const int* __restrict__ cnt, float* __restrict__ dis) {
  int i = blockIdx.x * 256 + threadIdx.x;
  if (i < NN) dis[i] = rsqrtf((float)cnt[i]);
}
// exclusive prefix sum of (cnt[v]-1) over 50000 rows; writes row_ptr and cursor copy
__global__ __launch_bounds__(1024) void k_scan(const int* __restrict__ cnt,
                                               int* __restrict__ row_ptr,
                                               int* __restrict__ cur) {
  __shared__ int ls[1024];
  const int t = threadIdx.x;
  const int C = 49;  // 1024*49 = 50176 >= NN
  int base = t * C;
  int s = 0;
  for (int i = 0; i < C; ++i) {
    int idx = base + i;
    if (idx < NN) s += cnt[idx] - 1;
  }
  ls[t] = s;
  __syncthreads();
  for (int off = 1; off < 1024; off <<= 1) {
    int v = (t >= off) ? ls[t - off] : 0;
    __syncthreads();
    ls[t] += v;
    __syncthreads();
  }
  int run = (t == 0) ? 0 : ls[t - 1];
  for (int i = 0; i < C; ++i) {
    int idx = base + i;
    if (idx < NN) {
      row_ptr[idx] = run;
      cur[idx] = run;
      run += cnt[idx] - 1;
    }
  }
}
// place each edge into its dst bucket; val = dis[src] (dis[dst] applied in gather)
__global__ void k_fill(const int* __restrict__ ei, const float* __restrict__ dis,
                       int* __restrict__ cur, int* __restrict__ col,
                       float* __restrict__ val) {
  int e = blockIdx.x * 256 + threadIdx.x;
  if (e >= EE) return;
  int s = ei[e], d = ei[EE + e];
  int pos = atomicAdd(&cur[d], 1);
  col[pos] = s;
  val[pos] = dis[s];
}

// ---------------- CSR gather aggregation: one wave per node ----------------
// x[v] = dis[v] * ( dis[v]*xw[v] + sum_e val[e]*xw[col[e]] )
__global__ __launch_bounds__(256) void k_gather(const int* __restrict__ row_ptr,
                                                const int* __restrict__ cnt,
                                                const int* __restrict__ col,
                                                const float* __restrict__ val,
                                                const float* __restrict__ xw,
                                                const float* __restrict__ dis,
                                                float* __restrict__ x) {
  int node = blockIdx.x * 4 + (threadIdx.x >> 6);
  if (node >= NN) return;
  int l = threadIdx.x & 63;
  int c4 = l * 4;
  int beg = row_ptr[node];
  int num = cnt[node] - 1;
  float dv = dis[node];
  float4 a = ld4(&xw[(size_t)node * 256 + c4]);
  float4 acc = make_float4(a.x * dv, a.y * dv, a.z * dv, a.w * dv);
  int i = 0;
  for (; i + 2 <= num; i += 2) {  // 2-deep to overlap row loads
    int s0 = col[beg + i], s1 = col[beg + i + 1];
    float c0 = val[beg + i], c1 = val[beg + i + 1];
    float4 v0 = ld4(&xw[(size_t)s0 * 256 + c4]);
    float4 v1 = ld4(&xw[(size_t)s1 * 256 + c4]);
    acc.x += c0 * v0.x + c1 * v1.x;
    acc.y += c0 * v0.y + c1 * v1.y;
    acc.z += c0 * v0.z + c1 * v1.z;
    acc.w += c0 * v0.w + c1 * v1.w;
  }
  if (i < num) {
    int s0 = col[beg + i];
    float c0 = val[beg + i];
    float4 v0 = ld4(&xw[(size_t)s0 * 256 + c4]);
    acc.x += c0 * v0.x; acc.y += c0 * v0.y;
    acc.z += c0 * v0.z; acc.w += c0 * v0.w;
  }
  acc.x *= dv; acc.y *= dv; acc.z *= dv; acc.w *= dv;
  *(float4*)&x[(size_t)node * 256 + c4] = acc;
}

// ---------------- generic fp32 GEMM: C[M,Nn] = A[M,K] @ B[K,Nn] ----------------
__global__ __launch_bounds__(256, 2) void k_gemm(const float* __restrict__ A,
                                                 const float* __restrict__ B,
                                                 float* __restrict__ C,
                                                 int M, int K, int Nn) {
  __shared__ float As[128][36];
  const int t = threadIdx.x;
  const int ty = t >> 4, tx = t & 15;
  const int bm = blockIdx.x * 128, bn = blockIdx.y * 128;
  float acc[8][8] = {};
  for (int kc = 0; kc < K; kc += 32) {
#pragma unroll
    for (int q = 0; q < 4; ++q) {
      int idx = t + q * 256;
      int m = idx >> 3, kq = (idx & 7) * 4;
      float4 v = make_float4(0.f, 0.f, 0.f, 0.f);
      if (bm + m < M) v = ld4(&A[(size_t)(bm + m) * K + kc + kq]);
      *(float4*)&As[m][kq] = v;
    }
    __syncthreads();
#pragma unroll
    for (int k4 = 0; k4 < 8; ++k4) {
      float4 av[8];
#pragma unroll
      for (int i = 0; i < 8; ++i) av[i] = *(const float4*)&As[ty * 8 + i][k4 * 4];
#pragma unroll
      for (int kk = 0; kk < 4; ++kk) {
        int kg = kc + k4 * 4 + kk;
        float4 b0 = ld4(&B[(size_t)kg * Nn + bn + tx * 8]);
        float4 bh = ld4(&B[(size_t)kg * Nn + bn + tx * 8 + 4]);
#pragma unroll
        for (int i = 0; i < 8; ++i) {
          float a = getc(av[i], kk);
          acc[i][0] += a * b0.x; acc[i][1] += a * b0.y;
          acc[i][2] += a * b0.z; acc[i][3] += a * b0.w;
          acc[i][4] += a * bh.x; acc[i][5] += a * bh.y;
          acc[i][6] += a * bh.z; acc[i][7] += a * bh.w;
        }
      }
    }
    __syncthreads();
  }
#pragma unroll
  for (int i = 0; i < 8; ++i) {
    int r = bm + ty * 8 + i;
    if (r < M) {
      *(float4*)&C[(size_t)r * Nn + bn + tx * 8] =
          make_float4(acc[i][0], acc[i][1], acc[i][2], acc[i][3]);
      *(float4*)&C[(size_t)r * Nn + bn + tx * 8 + 4] =
          make_float4(acc[i][4], acc[i][5], acc[i][6], acc[i][7]);
    }
  }
}

// ---------------- same GEMM, bf16 output (for P|Q) ----------------
__global__ __launch_bounds__(256, 2) void k_gemm_bf16(const float* __restrict__ A,
                                                      const float* __restrict__ B,
                                                      unsigned short* __restrict__ C,
                                                      int M, int K, int Nn) {
  __shared__ float As[128][36];
  const int t = threadIdx.x;
  const int ty = t >> 4, tx = t & 15;
  const int bm = blockIdx.x * 128, bn = blockIdx.y * 128;
  float acc[8][8] = {};
  for (int kc = 0; kc < K; kc += 32) {
#pragma unroll
    for (int q = 0; q < 4; ++q) {
      int idx = t + q * 256;
      int m = idx >> 3, kq = (idx & 7) * 4;
      float4 v = make_float4(0.f, 0.f, 0.f, 0.f);
      if (bm + m < M) v = ld4(&A[(size_t)(bm + m) * K + kc + kq]);
      *(float4*)&As[m][kq] = v;
    }
    __syncthreads();
#pragma unroll
    for (int k4 = 0; k4 < 8; ++k4) {
      float4 av[8];
#pragma unroll
      for (int i = 0; i < 8; ++i) av[i] = *(const float4*)&As[ty * 8 + i][k4 * 4];
#pragma unroll
      for (int kk = 0; kk < 4; ++kk) {
        int kg = kc + k4 * 4 + kk;
        float4 b0 = ld4(&B[(size_t)kg * Nn + bn + tx * 8]);
        float4 bh = ld4(&B[(size_t)kg * Nn + bn + tx * 8 + 4]);
#pragma unroll
        for (int i = 0; i < 8; ++i) {
          float a = getc(av[i], kk);
          acc[i][0] += a * b0.x; acc[i][1] += a * b0.y;
          acc[i][2] += a * b0.z; acc[i][3] += a * b0.w;
          acc[i][4] += a * bh.x; acc[i][5] += a * bh.y;
          acc[i][6] += a * bh.z; acc[i][7] += a * bh.w;
        }
      }
    }
    __syncthreads();
  }
#pragma unroll
  for (int i = 0; i < 8; ++i) {
    int r = bm + ty * 8 + i;
    if (r < M) {
      unsigned int w0 = (unsigned int)f2bf(acc[i][0]) | ((unsigned int)f2bf(acc[i][1]) << 16);
      unsigned int w1 = (unsigned int)f2bf(acc[i][2]) | ((unsigned int)f2bf(acc[i][3]) << 16);
      unsigned int w2 = (unsigned int)f2bf(acc[i][4]) | ((unsigned int)f2bf(acc[i][5]) << 16);
      unsigned int w3 = (unsigned int)f2bf(acc[i][6]) | ((unsigned int)f2bf(acc[i][7]) << 16);
      *(uint4*)&C[(size_t)r * Nn + bn + tx * 8] = make_uint4(w0, w1, w2, w3);
    }
  }
}

// ---------------- BatchNorm (training-mode) + ReLU ----------------
__global__ void k_bn_zero(float* __restrict__ s) {
  int i = blockIdx.x * 256 + threadIdx.x;
  if (i < 512) s[i] = 0.f;
}
__global__ void k_bn_stat(const float* __restrict__ x, float* __restrict__ sums) {
  int c = threadIdx.x;
  float s = 0.f, s2 = 0.f;
  for (int r = blockIdx.x; r < NN; r += gridDim.x) {
    float v = x[(size_t)r * HH + c];
    s += v; s2 += v * v;
  }
  atomicAdd(&sums[c], s);
  atomicAdd(&sums[HH + c], s2);
}
__global__ void k_bn_final(const float* __restrict__ sums, const float* __restrict__ gamma,
                           const float* __restrict__ beta, float* __restrict__ ss) {
  int c = threadIdx.x;
  float mu = sums[c] * (1.0f / NN);
  float var = sums[HH + c] * (1.0f / NN) - mu * mu;
  float s = gamma[c] * rsqrtf(var + EPSB);
  ss[c] = s;
  ss[HH + c] = beta[c] - mu * s;
}
__global__ void k_bn_apply(float* __restrict__ x, const float* __restrict__ ss) {
  int i = blockIdx.x * 256 + threadIdx.x;  // float4 index
  if (i < NN * 64) {
    int c4 = (i & 63) * 4;
    float4 sc = ld4(&ss[c4]);
    float4 sh = ld4(&ss[HH + c4]);
    float4 v = ld4(&x[(size_t)i * 4]);
    v.x = fmaxf(v.x * sc.x + sh.x, 0.f);
    v.y = fmaxf(v.y * sc.y + sh.y, 0.f);
    v.z = fmaxf(v.z * sc.z + sh.z, 0.f);
    v.w = fmaxf(v.w * sc.w + sh.w, 0.f);
    *(float4*)&x[(size_t)i * 4] = v;
  }
}

// ---------------- repack W1 -> [256][1024]: cols 0..511 = P-weights, 512.. = Q-weights
__global__ void k_w1repack(const float* __restrict__ W1, float* __restrict__ w1r) {
  int idx = blockIdx.x * 256 + threadIdx.x;
  if (idx < 256 * 1024) {
    int k = idx >> 10, j = idx & 1023;
    w1r[idx] = (j < 512) ? W1[k * 512 + j] : W1[(256 + k) * 512 + (j - 512)];
  }
}

// ---------------- weight -> MFMA-fragment-linear bf16 packs ----------------
__global__ void k_w2frag(const float* __restrict__ W2, unsigned short* __restrict__ W2f) {
  int u = blockIdx.x * 256 + threadIdx.x;  // [0, 16384)
  int lane = u & 63, ksg = (u >> 6) & 15, nt = u >> 10;
  int g = lane >> 4, li = lane & 15;
  unsigned int wd[4];
#pragma unroll
  for (int jj = 0; jj < 4; ++jj) {
    float a = W2[(size_t)(ksg * 32 + g * 8 + jj * 2) * 256 + nt * 16 + li];
    float b = W2[(size_t)(ksg * 32 + g * 8 + jj * 2 + 1) * 256 + nt * 16 + li];
    wd[jj] = (unsigned int)f2bf(a) | ((unsigned int)f2bf(b) << 16);
  }
  *(uint4*)&W2f[(size_t)u * 8] = make_uint4(wd[0], wd[1], wd[2], wd[3]);
}
__global__ void k_w3frag(const float* __restrict__ W3, unsigned short* __restrict__ W3f) {
  int u = blockIdx.x * 256 + threadIdx.x;  // [0, 4096)
  int lane = u & 63, ks = (u >> 6) & 7, mt = u >> 9;
  int g = lane >> 4, li = lane & 15;
  unsigned int wd[4];
#pragma unroll
  for (int jj = 0; jj < 4; ++jj) {
    float a = W3[(size_t)(ks * 32 + g * 8 + jj * 2) * 128 + mt * 16 + li];
    float b = W3[(size_t)(ks * 32 + g * 8 + jj * 2 + 1) * 128 + mt * 16 + li];
    wd[jj] = (unsigned int)f2bf(a) | ((unsigned int)f2bf(b) << 16);
  }
  *(uint4*)&W3f[(size_t)u * 8] = make_uint4(wd[0], wd[1], wd[2], wd[3]);
}

// ---------------- fused edge MLP, MFMA version: 64 edges / block ----------------
__global__ __launch_bounds__(256, 2) void k_edge(
    const int* __restrict__ ei, const unsigned short* __restrict__ pq,
    const float* __restrict__ b1, const unsigned short* __restrict__ W2f,
    const float* __restrict__ b2, const unsigned short* __restrict__ W3f,
    const float* __restrict__ b3, const float* __restrict__ W4,
    const float* __restrict__ b4, float* __restrict__ out) {
  __shared__ uint4 h1q[2048];       // 32 KB: h1 half-tile [64 e][256 k] bf16, swizzled
  __shared__ uint4 h2q[2048];       // 32 KB: h2 [64 e][256 n] bf16, swizzled
  __shared__ float red[64][17];
  __shared__ int es[64], ed[64];
  char* h1b = (char*)h1q;
  char* h2b = (char*)h2q;
  const int t = threadIdx.x;
  const int e0 = blockIdx.x * 64;
  if (t < 64) {
    int e = e0 + t;
    es[t] = (e < EE) ? ei[e] : 0;
    ed[t] = (e < EE) ? ei[EE + e] : 0;
  }
  __syncthreads();

  const int w = t >> 6, l = t & 63, g = l >> 4, li = l & 15;

  f4v acc2[4][4];
#pragma unroll
  for (int a = 0; a < 4; ++a)
#pragma unroll
    for (int b = 0; b < 4; ++b)
#pragma unroll
      for (int r = 0; r < 4; ++r) acc2[a][b][r] = 0.f;

  for (int half = 0; half < 2; ++half) {
    {  // build h1 half: relu(P[src]+Q[dst]+b1), bf16, XOR-swizzled by edge row
      int e = t >> 2, q = t & 3;
      size_t bp = (size_t)es[e] * 1024 + half * 256;
      size_t bq = (size_t)ed[e] * 1024 + 512 + half * 256;
      int sw = (e & 7) << 4;
#pragma unroll
      for (int j = 0; j < 8; ++j) {
        int kk = q * 64 + j * 8;
        uint4 pu = *(const uint4*)&pq[bp + kk];
        uint4 qu = *(const uint4*)&pq[bq + kk];
        float4 c0 = ld4(&b1[half * 256 + kk]);
        float4 c1 = ld4(&b1[half * 256 + kk + 4]);
        unsigned int r0 = pk2(bflo(pu.x) + bflo(qu.x) + c0.x, bfhi(pu.x) + bfhi(qu.x) + c0.y);
        unsigned int r1 = pk2(bflo(pu.y) + bflo(qu.y) + c0.z, bfhi(pu.y) + bfhi(qu.y) + c0.w);
        unsigned int r2 = pk2(bflo(pu.z) + bflo(qu.z) + c1.x, bfhi(pu.z) + bfhi(qu.z) + c1.y);
        unsigned int r3 = pk2(bflo(pu.w) + bflo(qu.w) + c1.z, bfhi(pu.w) + bfhi(qu.w) + c1.w);
        *(uint4*)(h1b + ((e * 512 + kk * 2) ^ sw)) = make_uint4(r0, r1, r2, r3);
      }
    }
    __syncthreads();
#pragma unroll
    for (int ks = 0; ks < 8; ++ks) {
      s8v af[4], bf[4];
#pragma unroll
      for (int a = 0; a < 4; ++a)
        af[a] = *(const s8v*)&W2f[(size_t)(((w * 4 + a) * 16 + half * 8 + ks) * 64 + l) * 8];
#pragma unroll
      for (int b = 0; b < 4; ++b)
        bf[b] = *(const s8v*)(h1b + ((((b * 16 + li) * 512) + ks * 64 + g * 16) ^ ((li & 7) << 4)));
#pragma unroll
      for (int a = 0; a < 4; ++a)
#pragma unroll
        for (int b = 0; b < 4; ++b)
          acc2[a][b] = __builtin_amdgcn_mfma_f32_16x16x32_bf16(af[a], bf[b], acc2[a][b], 0, 0, 0);
    }
    __syncthreads();
  }

#pragma unroll
  for (int a = 0; a < 4; ++a) {
    int nb = w * 64 + a * 16 + g * 4;
    float4 bv = ld4(&b2[nb]);
#pragma unroll
    for (int b = 0; b < 4; ++b) {
      f4v v = acc2[a][b];
      uint2 pkd;
      pkd.x = pk2(v[0] + bv.x, v[1] + bv.y);
      pkd.y = pk2(v[2] + bv.z, v[3] + bv.w);
      *(uint2*)(h2b + ((((b * 16 + li) * 512) + nb * 2) ^ ((li & 7) << 4))) = pkd;
    }
  }
  __syncthreads();

  f4v acc3[2][4];
#pragma unroll
  for (int c = 0; c < 2; ++c)
#pragma unroll
    for (int b = 0; b < 4; ++b)
#pragma unroll
      for (int r = 0; r < 4; ++r) acc3[c][b][r] = 0.f;
#pragma unroll
  for (int ks = 0; ks < 8; ++ks) {
    s8v am[2], be[4];
#pragma unroll
    for (int c = 0; c < 2; ++c)
      am[c] = *(const s8v*)&W3f[(size_t)(((w * 2 + c) * 8 + ks) * 64 + l) * 8];
#pragma unroll
    for (int b = 0; b < 4; ++b)
      be[b] = *(const s8v*)(h2b + ((((b * 16 + li) * 512) + ks * 64 + g * 16) ^ ((li & 7) << 4)));
#pragma unroll
    for (int c = 0; c < 2; ++c)
#pragma unroll
      for (int b = 0; b < 4; ++b)
        acc3[c][b] = __builtin_amdgcn_mfma_f32_16x16x32_bf16(am[c], be[b], acc3[c][b], 0, 0, 0);
  }

  float part[4] = {0.f, 0.f, 0.f, 0.f};
#pragma unroll
  for (int c = 0; c < 2; ++c) {
    int mb = (w * 2 + c) * 16 + g * 4;
    float4 b3v = ld4(&b3[mb]);
    float4 w4v = ld4(&W4[mb]);
#pragma unroll
    for (int b = 0; b < 4; ++b) {
      f4v v = acc3[c][b];
      part[b] += fmaxf(v[0] + b3v.x, 0.f) * w4v.x + fmaxf(v[1] + b3v.y, 0.f) * w4v.y +
                 fmaxf(v[2] + b3v.z, 0.f) * w4v.z + fmaxf(v[3] + b3v.w, 0.f) * w4v.w;
    }
  }
#pragma unroll
  for (int b = 0; b < 4; ++b) red[b * 16 + li][w * 4 + g] = part[b];
  __syncthreads();
  if (t < 64) {
    float s = 0.f;
#pragma unroll
    for (int x = 0; x < 16; ++x) s += red[t][x];
    int e = e0 + t;
    if (e < EE) out[e] = s + b4[0];
  }
}

extern "C" void kernel_launch(void* const* d_in, const int* in_sizes, int n_in,
                              void* d_out, int out_size, void* d_ws, size_t ws_size,
                              hipStream_t stream) {
  const int* ei = (const int*)d_in[0];
  const float* node_emb = (const float*)d_in[1];
  const float* convW = (const float*)d_in[2];
  // d_in[3] = convB: cancels exactly in training-mode BN -> unused
  const float* bn_gamma = (const float*)d_in[4];
  const float* bn_beta = (const float*)d_in[5];
  const float* W1 = (const float*)d_in[6];
  const float* b1 = (const float*)d_in[7];
  const float* W2 = (const float*)d_in[8];
  const float* b2 = (const float*)d_in[9];
  const float* W3 = (const float*)d_in[10];
  const float* b3 = (const float*)d_in[11];
  const float* W4 = (const float*)d_in[12];
  const float* b4 = (const float*)d_in[13];
  float* out = (float*)d_out;

  char* w = (char*)d_ws;
  float* x_buf = (float*)w;             w += 51200000;   // [50000][256] fp32
  char* uni = w;                        w += 102400000;  // union region
  float* xw = (float*)uni;                               // [50000][256] fp32 (layers)
  unsigned short* pqb = (unsigned short*)uni;            // [50000][1024] bf16 (P|Q)
  float* w1r   = (float*)w; w += 1048576;    // [256][1024]
  float* dis   = (float*)w; w += 200704;     // [50000]
  int*   cnt   = (int*)w;   w += 200704;     // [50000]
  float* bnsum = (float*)w; w += 4096;       // [512]
  float* bnss  = (float*)w; w += 4096;       // [512]
  unsigned short* W2f = (unsigned short*)w; w += 262144;  // frag-linear bf16 W2
  unsigned short* W3f = (unsigned short*)w; w += 65536;   // frag-linear bf16 W3
  int*   row_ptr = (int*)w; w += 200704;     // [50000]
  int*   curp    = (int*)w; w += 200704;     // [50000]
  int*   colv    = (int*)w; w += 2000896;    // [500000]
  float* valv    = (float*)w; w += 2000896;  // [500000]
  (void)ws_size; (void)in_sizes; (void)n_in; (void)out_size;

  // CSR build (per call; ws is re-poisoned each launch)
  k_cnt_init<<<196, 256, 0, stream>>>(cnt);
  k_cnt<<<(EE + 255) / 256, 256, 0, stream>>>(ei + EE, cnt);
  k_dis<<<196, 256, 0, stream>>>(cnt, dis);
  k_scan<<<1, 1024, 0, stream>>>(cnt, row_ptr, curp);
  k_fill<<<(EE + 255) / 256, 256, 0, stream>>>(ei, dis, curp, colv, valv);
  k_w2frag<<<64, 256, 0, stream>>>(W2, W2f);
  k_w3frag<<<16, 256, 0, stream>>>(W3, W3f);

  for (int l = 0; l < 2; ++l) {
    const float* A = (l == 0) ? node_emb : x_buf;
    k_gemm<<<dim3(391, 2), 256, 0, stream>>>(A, convW + l * HH * HH, xw, NN, HH, HH);
    k_gather<<<12500, 256, 0, stream>>>(row_ptr, cnt, colv, valv, xw, dis, x_buf);
    k_bn_zero<<<2, 256, 0, stream>>>(bnsum);
    k_bn_stat<<<512, 256, 0, stream>>>(x_buf, bnsum);
    k_bn_final<<<1, 256, 0, stream>>>(bnsum, bn_gamma + l * HH, bn_beta + l * HH, bnss);
    k_bn_apply<<<12500, 256, 0, stream>>>(x_buf, bnss);
  }

  k_w1repack<<<1024, 256, 0, stream>>>(W1, w1r);
  k_gemm_bf16<<<dim3(391, 8), 256, 0, stream>>>(x_buf, w1r, pqb, NN, HH, 1024);
  k_edge<<<7813, 256, 0, stream>>>(ei, pqb, b1, W2f, b2, W3f, b3, W4, b4, out);
}

// Round 10
// 1470.205 us; speedup vs baseline: 4.7488x; 1.1431x over previous
//
#include <hip/hip_runtime.h>

#define NN 50000
#define HH 256
#define EE 500000
#define EPSB 1e-5f

typedef __attribute__((ext_vector_type(8))) short s8v;   // 8 bf16 (4 VGPR)
typedef __attribute__((ext_vector_type(4))) float f4v;   // MFMA acc

__device__ __forceinline__ float4 ld4(const float* p) { return *(const float4*)p; }

__device__ __forceinline__ float getc(const float4& v, int kk) {
  return kk == 0 ? v.x : kk == 1 ? v.y : kk == 2 ? v.z : v.w;
}

__device__ __forceinline__ unsigned short f2bf(float f) {
  unsigned int u = __float_as_uint(f);
  unsigned int r = (u + 0x7FFFu + ((u >> 16) & 1u)) >> 16;
  return (unsigned short)r;
}
__device__ __forceinline__ float bf2f(unsigned short s) {
  return __uint_as_float(((unsigned int)s) << 16);
}
__device__ __forceinline__ float bflo(unsigned int u) { return __uint_as_float(u << 16); }
__device__ __forceinline__ float bfhi(unsigned int u) { return __uint_as_float(u & 0xFFFF0000u); }
__device__ __forceinline__ unsigned int pk2(float a, float b) {  // relu + pack
  return (unsigned int)f2bf(fmaxf(a, 0.f)) | ((unsigned int)f2bf(fmaxf(b, 0.f)) << 16);
}
__device__ __forceinline__ unsigned int pk2n(float a, float b) {  // pack, no relu
  return (unsigned int)f2bf(a) | ((unsigned int)f2bf(b) << 16);
}

// ---------------- degree / CSR build ----------------
__global__ void k_cnt_init(int* __restrict__ cnt) {
  int i = blockIdx.x * 256 + threadIdx.x;
  if (i < NN) cnt[i] = 1;  // self-loop
}
__global__ void k_cnt(const int* __restrict__ dst, int* __restrict__ cnt) {
  int e = blockIdx.x * 256 + threadIdx.x;
  if (e < EE) atomicAdd(&cnt[dst[e]], 1);
}
__global__ void k_dis(const int* __restrict__ cnt, float* __restrict__ dis) {
  int i = blockIdx.x * 256 + threadIdx.x;
  if (i < NN) dis[i] = rsqrtf((float)cnt[i]);
}
// exclusive prefix sum of (cnt[v]-1); writes row_ptr and cursor copy
__global__ __launch_bounds__(1024) void k_scan(const int* __restrict__ cnt,
                                               int* __restrict__ row_ptr,
                                               int* __restrict__ cur) {
  __shared__ int ls[1024];
  const int t = threadIdx.x;
  const int C = 49;  // 1024*49 >= NN
  int base = t * C;
  int s = 0;
  for (int i = 0; i < C; ++i) {
    int idx = base + i;
    if (idx < NN) s += cnt[idx] - 1;
  }
  ls[t] = s;
  __syncthreads();
  for (int off = 1; off < 1024; off <<= 1) {
    int v = (t >= off) ? ls[t - off] : 0;
    __syncthreads();
    ls[t] += v;
    __syncthreads();
  }
  int run = (t == 0) ? 0 : ls[t - 1];
  for (int i = 0; i < C; ++i) {
    int idx = base + i;
    if (idx < NN) {
      row_ptr[idx] = run;
      cur[idx] = run;
      run += cnt[idx] - 1;
    }
  }
}
__global__ void k_fill(const int* __restrict__ ei, const float* __restrict__ dis,
                       int* __restrict__ cur, int* __restrict__ col,
                       float* __restrict__ val) {
  int e = blockIdx.x * 256 + threadIdx.x;
  if (e >= EE) return;
  int s = ei[e], d = ei[EE + e];
  int pos = atomicAdd(&cur[d], 1);
  col[pos] = s;
  val[pos] = dis[s];
}

// ---------------- CSR gather aggregation: one wave per node ----------------
__global__ __launch_bounds__(256) void k_gather(const int* __restrict__ row_ptr,
                                                const int* __restrict__ cnt,
                                                const int* __restrict__ col,
                                                const float* __restrict__ val,
                                                const float* __restrict__ xw,
                                                const float* __restrict__ dis,
                                                float* __restrict__ x) {
  int node = blockIdx.x * 4 + (threadIdx.x >> 6);
  if (node >= NN) return;
  int l = threadIdx.x & 63;
  int c4 = l * 4;
  int beg = row_ptr[node];
  int num = cnt[node] - 1;
  float dv = dis[node];
  float4 a = ld4(&xw[(size_t)node * 256 + c4]);
  float4 acc = make_float4(a.x * dv, a.y * dv, a.z * dv, a.w * dv);
  int i = 0;
  for (; i + 2 <= num; i += 2) {
    int s0 = col[beg + i], s1 = col[beg + i + 1];
    float c0 = val[beg + i], c1 = val[beg + i + 1];
    float4 v0 = ld4(&xw[(size_t)s0 * 256 + c4]);
    float4 v1 = ld4(&xw[(size_t)s1 * 256 + c4]);
    acc.x += c0 * v0.x + c1 * v1.x;
    acc.y += c0 * v0.y + c1 * v1.y;
    acc.z += c0 * v0.z + c1 * v1.z;
    acc.w += c0 * v0.w + c1 * v1.w;
  }
  if (i < num) {
    int s0 = col[beg + i];
    float c0 = val[beg + i];
    float4 v0 = ld4(&xw[(size_t)s0 * 256 + c4]);
    acc.x += c0 * v0.x; acc.y += c0 * v0.y;
    acc.z += c0 * v0.z; acc.w += c0 * v0.w;
  }
  acc.x *= dv; acc.y *= dv; acc.z *= dv; acc.w *= dv;
  *(float4*)&x[(size_t)node * 256 + c4] = acc;
}

// ---------------- generic fp32 GEMM (conv layers) ----------------
__global__ __launch_bounds__(256, 2) void k_gemm(const float* __restrict__ A,
                                                 const float* __restrict__ B,
                                                 float* __restrict__ C,
                                                 int M, int K, int Nn) {
  __shared__ float As[128][36];
  const int t = threadIdx.x;
  const int ty = t >> 4, tx = t & 15;
  const int bm = blockIdx.x * 128, bn = blockIdx.y * 128;
  float acc[8][8] = {};
  for (int kc = 0; kc < K; kc += 32) {
#pragma unroll
    for (int q = 0; q < 4; ++q) {
      int idx = t + q * 256;
      int m = idx >> 3, kq = (idx & 7) * 4;
      float4 v = make_float4(0.f, 0.f, 0.f, 0.f);
      if (bm + m < M) v = ld4(&A[(size_t)(bm + m) * K + kc + kq]);
      *(float4*)&As[m][kq] = v;
    }
    __syncthreads();
#pragma unroll
    for (int k4 = 0; k4 < 8; ++k4) {
      float4 av[8];
#pragma unroll
      for (int i = 0; i < 8; ++i) av[i] = *(const float4*)&As[ty * 8 + i][k4 * 4];
#pragma unroll
      for (int kk = 0; kk < 4; ++kk) {
        int kg = kc + k4 * 4 + kk;
        float4 b0 = ld4(&B[(size_t)kg * Nn + bn + tx * 8]);
        float4 bh = ld4(&B[(size_t)kg * Nn + bn + tx * 8 + 4]);
#pragma unroll
        for (int i = 0; i < 8; ++i) {
          float a = getc(av[i], kk);
          acc[i][0] += a * b0.x; acc[i][1] += a * b0.y;
          acc[i][2] += a * b0.z; acc[i][3] += a * b0.w;
          acc[i][4] += a * bh.x; acc[i][5] += a * bh.y;
          acc[i][6] += a * bh.z; acc[i][7] += a * bh.w;
        }
      }
    }
    __syncthreads();
  }
#pragma unroll
  for (int i = 0; i < 8; ++i) {
    int r = bm + ty * 8 + i;
    if (r < M) {
      *(float4*)&C[(size_t)r * Nn + bn + tx * 8] =
          make_float4(acc[i][0], acc[i][1], acc[i][2], acc[i][3]);
      *(float4*)&C[(size_t)r * Nn + bn + tx * 8 + 4] =
          make_float4(acc[i][4], acc[i][5], acc[i][6], acc[i][7]);
    }
  }
}

// ---------------- BatchNorm (training-mode) + ReLU ----------------
__global__ void k_bn_zero(float* __restrict__ s) {
  int i = blockIdx.x * 256 + threadIdx.x;
  if (i < 512) s[i] = 0.f;
}
__global__ void k_bn_stat(const float* __restrict__ x, float* __restrict__ sums) {
  int c = threadIdx.x;
  float s = 0.f, s2 = 0.f;
  for (int r = blockIdx.x; r < NN; r += gridDim.x) {
    float v = x[(size_t)r * HH + c];
    s += v; s2 += v * v;
  }
  atomicAdd(&sums[c], s);
  atomicAdd(&sums[HH + c], s2);
}
__global__ void k_bn_final(const float* __restrict__ sums, const float* __restrict__ gamma,
                           const float* __restrict__ beta, float* __restrict__ ss) {
  int c = threadIdx.x;
  float mu = sums[c] * (1.0f / NN);
  float var = sums[HH + c] * (1.0f / NN) - mu * mu;
  float s = gamma[c] * rsqrtf(var + EPSB);
  ss[c] = s;
  ss[HH + c] = beta[c] - mu * s;
}
__global__ void k_bn_apply(float* __restrict__ x, const float* __restrict__ ss) {
  int i = blockIdx.x * 256 + threadIdx.x;  // float4 index
  if (i < NN * 64) {
    int c4 = (i & 63) * 4;
    float4 sc = ld4(&ss[c4]);
    float4 sh = ld4(&ss[HH + c4]);
    float4 v = ld4(&x[(size_t)i * 4]);
    v.x = fmaxf(v.x * sc.x + sh.x, 0.f);
    v.y = fmaxf(v.y * sc.y + sh.y, 0.f);
    v.z = fmaxf(v.z * sc.z + sh.z, 0.f);
    v.w = fmaxf(v.w * sc.w + sh.w, 0.f);
    *(float4*)&x[(size_t)i * 4] = v;
  }
}

// ---------------- weight -> MFMA-fragment-linear bf16 packs ----------------
// W1f: B-operand frags for the P/Q GEMM, fusing the P|Q column permutation:
// w1r[k][n] = n<512 ? W1[k][n] : W1[256+k][n-512].
// u = (nt*8 + ks)*64 + lane; elem j = w1r[ks*32 + (lane>>4)*8 + j][nt*16 + (lane&15)]
__global__ void k_w1frag(const float* __restrict__ W1, unsigned short* __restrict__ W1f) {
  int u = blockIdx.x * 256 + threadIdx.x;  // [0, 32768)
  int lane = u & 63, ks = (u >> 6) & 7, nt = u >> 9;
  int g = lane >> 4, li = lane & 15;
  int n = nt * 16 + li;
  size_t cadd = (n < 512) ? (size_t)n : (size_t)(n - 512) + 256 * 512;
  unsigned int wd[4];
#pragma unroll
  for (int jj = 0; jj < 4; ++jj) {
    int k0 = ks * 32 + g * 8 + jj * 2;
    float a = W1[(size_t)k0 * 512 + cadd];
    float b = W1[(size_t)(k0 + 1) * 512 + cadd];
    wd[jj] = pk2n(a, b);
  }
  *(uint4*)&W1f[(size_t)u * 8] = make_uint4(wd[0], wd[1], wd[2], wd[3]);
}
// W2f: A-operand frags for edge gemm2
__global__ void k_w2frag(const float* __restrict__ W2, unsigned short* __restrict__ W2f) {
  int u = blockIdx.x * 256 + threadIdx.x;  // [0, 16384)
  int lane = u & 63, ksg = (u >> 6) & 15, nt = u >> 10;
  int g = lane >> 4, li = lane & 15;
  unsigned int wd[4];
#pragma unroll
  for (int jj = 0; jj < 4; ++jj) {
    float a = W2[(size_t)(ksg * 32 + g * 8 + jj * 2) * 256 + nt * 16 + li];
    float b = W2[(size_t)(ksg * 32 + g * 8 + jj * 2 + 1) * 256 + nt * 16 + li];
    wd[jj] = pk2n(a, b);
  }
  *(uint4*)&W2f[(size_t)u * 8] = make_uint4(wd[0], wd[1], wd[2], wd[3]);
}
// W3f: A-operand frags for edge gemm3
__global__ void k_w3frag(const float* __restrict__ W3, unsigned short* __restrict__ W3f) {
  int u = blockIdx.x * 256 + threadIdx.x;  // [0, 4096)
  int lane = u & 63, ks = (u >> 6) & 7, mt = u >> 9;
  int g = lane >> 4, li = lane & 15;
  unsigned int wd[4];
#pragma unroll
  for (int jj = 0; jj < 4; ++jj) {
    float a = W3[(size_t)(ks * 32 + g * 8 + jj * 2) * 128 + mt * 16 + li];
    float b = W3[(size_t)(ks * 32 + g * 8 + jj * 2 + 1) * 128 + mt * 16 + li];
    wd[jj] = pk2n(a, b);
  }
  *(uint4*)&W3f[(size_t)u * 8] = make_uint4(wd[0], wd[1], wd[2], wd[3]);
}

// ---------------- P/Q GEMM via MFMA: pqb[50000][1024] = x_buf @ w1r, bf16 out
// 128x128 tile, 4 waves (2x2), A staged bf16 in LDS (XOR swizzle), B frag-linear
// from W1f (L2-resident). C round-trips through LDS (reusing A space) for
// coalesced bf16 stores.
__global__ __launch_bounds__(256, 2) void k_pq(const float* __restrict__ A,
                                               const unsigned short* __restrict__ W1f,
                                               unsigned short* __restrict__ C) {
  __shared__ uint4 ldsq[4096];  // 64 KB: A tile [128][256] bf16 swz, then C [128][128] f32 swz
  char* lds = (char*)ldsq;
  const int t = threadIdx.x;
  const int bm = blockIdx.x * 128;
  const int w = t >> 6, l = t & 63, g = l >> 4, li = l & 15;
  const int wm = w >> 1, wn = w & 1;

  {  // stage A[bm..bm+128][0..256] -> bf16 LDS, byte ^= (row&7)<<4
    int r = t >> 1, h = t & 1;
    int row = bm + r;
    int sw = (r & 7) << 4;
    const float* src = &A[(size_t)row * 256 + h * 128];
#pragma unroll
    for (int j = 0; j < 16; ++j) {
      float4 v0 = make_float4(0.f, 0.f, 0.f, 0.f), v1 = v0;
      if (row < NN) { v0 = ld4(src + j * 8); v1 = ld4(src + j * 8 + 4); }
      uint4 pk;
      pk.x = pk2n(v0.x, v0.y); pk.y = pk2n(v0.z, v0.w);
      pk.z = pk2n(v1.x, v1.y); pk.w = pk2n(v1.z, v1.w);
      *(uint4*)(lds + ((r * 512 + h * 256 + j * 16) ^ sw)) = pk;
    }
  }
  __syncthreads();

  f4v acc[4][4];
#pragma unroll
  for (int a = 0; a < 4; ++a)
#pragma unroll
    for (int b = 0; b < 4; ++b)
#pragma unroll
      for (int r = 0; r < 4; ++r) acc[a][b][r] = 0.f;

#pragma unroll
  for (int ks = 0; ks < 8; ++ks) {
    s8v af[4], bf[4];
#pragma unroll
    for (int a = 0; a < 4; ++a) {
      int row = wm * 64 + a * 16 + li;
      af[a] = *(const s8v*)(lds + ((row * 512 + ks * 64 + g * 16) ^ ((li & 7) << 4)));
    }
#pragma unroll
    for (int b = 0; b < 4; ++b) {
      int nt = blockIdx.y * 8 + wn * 4 + b;
      bf[b] = *(const s8v*)&W1f[(size_t)((nt * 8 + ks) * 64 + l) * 8];
    }
#pragma unroll
    for (int a = 0; a < 4; ++a)
#pragma unroll
      for (int b = 0; b < 4; ++b)
        acc[a][b] = __builtin_amdgcn_mfma_f32_16x16x32_bf16(af[a], bf[b], acc[a][b], 0, 0, 0);
  }
  __syncthreads();  // A dead; reuse LDS for C (fp32 [128 m][128 n], swz by m)

#pragma unroll
  for (int a = 0; a < 4; ++a)
#pragma unroll
    for (int b = 0; b < 4; ++b)
#pragma unroll
      for (int r = 0; r < 4; ++r) {
        int m = wm * 64 + a * 16 + g * 4 + r;
        int n = wn * 64 + b * 16 + li;
        *(float*)(lds + ((m * 512 + n * 4) ^ ((m & 7) << 4))) = acc[a][b][r];
      }
  __syncthreads();

  {  // coalesced bf16 store: thread t -> row t>>1, 64 cols
    int r = t >> 1, h = t & 1;
    int row = bm + r;
    if (row < NN) {
      unsigned short* dst = &C[(size_t)row * 1024 + blockIdx.y * 128 + h * 64];
      int sw = (r & 7) << 4;
#pragma unroll
      for (int j = 0; j < 8; ++j) {
        float4 v0 = *(const float4*)(lds + ((r * 512 + h * 256 + j * 32) ^ sw));
        float4 v1 = *(const float4*)(lds + ((r * 512 + h * 256 + j * 32 + 16) ^ sw));
        uint4 pk;
        pk.x = pk2n(v0.x, v0.y); pk.y = pk2n(v0.z, v0.w);
        pk.z = pk2n(v1.x, v1.y); pk.w = pk2n(v1.z, v1.w);
        *(uint4*)(dst + j * 8) = pk;
      }
    }
  }
}

// ---------------- fused edge MLP, MFMA version: 64 edges / block ----------------
__global__ __launch_bounds__(256, 2) void k_edge(
    const int* __restrict__ ei, const unsigned short* __restrict__ pq,
    const float* __restrict__ b1, const unsigned short* __restrict__ W2f,
    const float* __restrict__ b2, const unsigned short* __restrict__ W3f,
    const float* __restrict__ b3, const float* __restrict__ W4,
    const float* __restrict__ b4, float* __restrict__ out) {
  __shared__ uint4 h1q[2048];       // 32 KB
  __shared__ uint4 h2q[2048];       // 32 KB
  __shared__ float red[64][17];
  __shared__ int es[64], ed[64];
  char* h1b = (char*)h1q;
  char* h2b = (char*)h2q;
  const int t = threadIdx.x;
  const int e0 = blockIdx.x * 64;
  if (t < 64) {
    int e = e0 + t;
    es[t] = (e < EE) ? ei[e] : 0;
    ed[t] = (e < EE) ? ei[EE + e] : 0;
  }
  __syncthreads();

  const int w = t >> 6, l = t & 63, g = l >> 4, li = l & 15;

  f4v acc2[4][4];
#pragma unroll
  for (int a = 0; a < 4; ++a)
#pragma unroll
    for (int b = 0; b < 4; ++b)
#pragma unroll
      for (int r = 0; r < 4; ++r) acc2[a][b][r] = 0.f;

  for (int half = 0; half < 2; ++half) {
    {  // build h1 half: relu(P[src]+Q[dst]+b1), bf16, XOR-swizzled by edge row
      int e = t >> 2, q = t & 3;
      size_t bp = (size_t)es[e] * 1024 + half * 256;
      size_t bq = (size_t)ed[e] * 1024 + 512 + half * 256;
      int sw = (e & 7) << 4;
#pragma unroll
      for (int j = 0; j < 8; ++j) {
        int kk = q * 64 + j * 8;
        uint4 pu = *(const uint4*)&pq[bp + kk];
        uint4 qu = *(const uint4*)&pq[bq + kk];
        float4 c0 = ld4(&b1[half * 256 + kk]);
        float4 c1 = ld4(&b1[half * 256 + kk + 4]);
        unsigned int r0 = pk2(bflo(pu.x) + bflo(qu.x) + c0.x, bfhi(pu.x) + bfhi(qu.x) + c0.y);
        unsigned int r1 = pk2(bflo(pu.y) + bflo(qu.y) + c0.z, bfhi(pu.y) + bfhi(qu.y) + c0.w);
        unsigned int r2 = pk2(bflo(pu.z) + bflo(qu.z) + c1.x, bfhi(pu.z) + bfhi(qu.z) + c1.y);
        unsigned int r3 = pk2(bflo(pu.w) + bflo(qu.w) + c1.z, bfhi(pu.w) + bfhi(qu.w) + c1.w);
        *(uint4*)(h1b + ((e * 512 + kk * 2) ^ sw)) = make_uint4(r0, r1, r2, r3);
      }
    }
    __syncthreads();
#pragma unroll
    for (int ks = 0; ks < 8; ++ks) {
      s8v af[4], bf[4];
#pragma unroll
      for (int a = 0; a < 4; ++a)
        af[a] = *(const s8v*)&W2f[(size_t)(((w * 4 + a) * 16 + half * 8 + ks) * 64 + l) * 8];
#pragma unroll
      for (int b = 0; b < 4; ++b)
        bf[b] = *(const s8v*)(h1b + ((((b * 16 + li) * 512) + ks * 64 + g * 16) ^ ((li & 7) << 4)));
#pragma unroll
      for (int a = 0; a < 4; ++a)
#pragma unroll
        for (int b = 0; b < 4; ++b)
          acc2[a][b] = __builtin_amdgcn_mfma_f32_16x16x32_bf16(af[a], bf[b], acc2[a][b], 0, 0, 0);
    }
    __syncthreads();
  }

#pragma unroll
  for (int a = 0; a < 4; ++a) {
    int nb = w * 64 + a * 16 + g * 4;
    float4 bv = ld4(&b2[nb]);
#pragma unroll
    for (int b = 0; b < 4; ++b) {
      f4v v = acc2[a][b];
      uint2 pkd;
      pkd.x = pk2(v[0] + bv.x, v[1] + bv.y);
      pkd.y = pk2(v[2] + bv.z, v[3] + bv.w);
      *(uint2*)(h2b + ((((b * 16 + li) * 512) + nb * 2) ^ ((li & 7) << 4))) = pkd;
    }
  }
  __syncthreads();

  f4v acc3[2][4];
#pragma unroll
  for (int c = 0; c < 2; ++c)
#pragma unroll
    for (int b = 0; b < 4; ++b)
#pragma unroll
      for (int r = 0; r < 4; ++r) acc3[c][b][r] = 0.f;
#pragma unroll
  for (int ks = 0; ks < 8; ++ks) {
    s8v am[2], be[4];
#pragma unroll
    for (int c = 0; c < 2; ++c)
      am[c] = *(const s8v*)&W3f[(size_t)(((w * 2 + c) * 8 + ks) * 64 + l) * 8];
#pragma unroll
    for (int b = 0; b < 4; ++b)
      be[b] = *(const s8v*)(h2b + ((((b * 16 + li) * 512) + ks * 64 + g * 16) ^ ((li & 7) << 4)));
#pragma unroll
    for (int c = 0; c < 2; ++c)
#pragma unroll
      for (int b = 0; b < 4; ++b)
        acc3[c][b] = __builtin_amdgcn_mfma_f32_16x16x32_bf16(am[c], be[b], acc3[c][b], 0, 0, 0);
  }

  float part[4] = {0.f, 0.f, 0.f, 0.f};
#pragma unroll
  for (int c = 0; c < 2; ++c) {
    int mb = (w * 2 + c) * 16 + g * 4;
    float4 b3v = ld4(&b3[mb]);
    float4 w4v = ld4(&W4[mb]);
#pragma unroll
    for (int b = 0; b < 4; ++b) {
      f4v v = acc3[c][b];
      part[b] += fmaxf(v[0] + b3v.x, 0.f) * w4v.x + fmaxf(v[1] + b3v.y, 0.f) * w4v.y +
                 fmaxf(v[2] + b3v.z, 0.f) * w4v.z + fmaxf(v[3] + b3v.w, 0.f) * w4v.w;
    }
  }
#pragma unroll
  for (int b = 0; b < 4; ++b) red[b * 16 + li][w * 4 + g] = part[b];
  __syncthreads();
  if (t < 64) {
    float s = 0.f;
#pragma unroll
    for (int x = 0; x < 16; ++x) s += red[t][x];
    int e = e0 + t;
    if (e < EE) out[e] = s + b4[0];
  }
}

extern "C" void kernel_launch(void* const* d_in, const int* in_sizes, int n_in,
                              void* d_out, int out_size, void* d_ws, size_t ws_size,
                              hipStream_t stream) {
  const int* ei = (const int*)d_in[0];
  const float* node_emb = (const float*)d_in[1];
  const float* convW = (const float*)d_in[2];
  // d_in[3] = convB: cancels exactly in training-mode BN -> unused
  const float* bn_gamma = (const float*)d_in[4];
  const float* bn_beta = (const float*)d_in[5];
  const float* W1 = (const float*)d_in[6];
  const float* b1 = (const float*)d_in[7];
  const float* W2 = (const float*)d_in[8];
  const float* b2 = (const float*)d_in[9];
  const float* W3 = (const float*)d_in[10];
  const float* b3 = (const float*)d_in[11];
  const float* W4 = (const float*)d_in[12];
  const float* b4 = (const float*)d_in[13];
  float* out = (float*)d_out;

  char* w = (char*)d_ws;
  float* x_buf = (float*)w;             w += 51200000;   // [50000][256] fp32
  char* uni = w;                        w += 102400000;  // union region
  float* xw = (float*)uni;                               // [50000][256] fp32 (layers)
  unsigned short* pqb = (unsigned short*)uni;            // [50000][1024] bf16 (P|Q)
  unsigned short* W1f = (unsigned short*)w; w += 524288;  // frag-linear bf16 W1 (P|Q fused)
  float* dis   = (float*)w; w += 200704;     // [50000]
  int*   cnt   = (int*)w;   w += 200704;     // [50000]
  float* bnsum = (float*)w; w += 4096;       // [512]
  float* bnss  = (float*)w; w += 4096;       // [512]
  unsigned short* W2f = (unsigned short*)w; w += 262144;  // frag-linear bf16 W2
  unsigned short* W3f = (unsigned short*)w; w += 65536;   // frag-linear bf16 W3
  int*   row_ptr = (int*)w; w += 200704;     // [50000]
  int*   curp    = (int*)w; w += 200704;     // [50000]
  int*   colv    = (int*)w; w += 2000896;    // [500000]
  float* valv    = (float*)w; w += 2000896;  // [500000]
  (void)ws_size; (void)in_sizes; (void)n_in; (void)out_size;

  // CSR build + weight fragment packs
  k_cnt_init<<<196, 256, 0, stream>>>(cnt);
  k_cnt<<<(EE + 255) / 256, 256, 0, stream>>>(ei + EE, cnt);
  k_dis<<<196, 256, 0, stream>>>(cnt, dis);
  k_scan<<<1, 1024, 0, stream>>>(cnt, row_ptr, curp);
  k_fill<<<(EE + 255) / 256, 256, 0, stream>>>(ei, dis, curp, colv, valv);
  k_w1frag<<<128, 256, 0, stream>>>(W1, W1f);
  k_w2frag<<<64, 256, 0, stream>>>(W2, W2f);
  k_w3frag<<<16, 256, 0, stream>>>(W3, W3f);

  for (int l = 0; l < 2; ++l) {
    const float* A = (l == 0) ? node_emb : x_buf;
    k_gemm<<<dim3(391, 2), 256, 0, stream>>>(A, convW + l * HH * HH, xw, NN, HH, HH);
    k_gather<<<12500, 256, 0, stream>>>(row_ptr, cnt, colv, valv, xw, dis, x_buf);
    k_bn_zero<<<2, 256, 0, stream>>>(bnsum);
    k_bn_stat<<<512, 256, 0, stream>>>(x_buf, bnsum);
    k_bn_final<<<1, 256, 0, stream>>>(bnsum, bn_gamma + l * HH, bn_beta + l * HH, bnss);
    k_bn_apply<<<12500, 256, 0, stream>>>(x_buf, bnss);
  }

  k_pq<<<dim3(391, 8), 256, 0, stream>>>(x_buf, W1f, pqb);
  k_edge<<<7813, 256, 0, stream>>>(ei, pqb, b1, W2f, b2, W3f, b3, W4, b4, out);
}

// Round 11
// 1090.063 us; speedup vs baseline: 6.4048x; 1.3487x over previous
//
#include <hip/hip_runtime.h>

#define NN 50000
#define HH 256
#define EE 500000
#define EPSB 1e-5f

typedef __attribute__((ext_vector_type(8))) short s8v;   // 8 bf16 (4 VGPR)
typedef __attribute__((ext_vector_type(4))) float f4v;   // MFMA acc

__device__ __forceinline__ float4 ld4(const float* p) { return *(const float4*)p; }

__device__ __forceinline__ unsigned short f2bf(float f) {
  unsigned int u = __float_as_uint(f);
  unsigned int r = (u + 0x7FFFu + ((u >> 16) & 1u)) >> 16;
  return (unsigned short)r;
}
__device__ __forceinline__ float bflo(unsigned int u) { return __uint_as_float(u << 16); }
__device__ __forceinline__ float bfhi(unsigned int u) { return __uint_as_float(u & 0xFFFF0000u); }
__device__ __forceinline__ unsigned int pk2(float a, float b) {  // relu + pack
  return (unsigned int)f2bf(fmaxf(a, 0.f)) | ((unsigned int)f2bf(fmaxf(b, 0.f)) << 16);
}
__device__ __forceinline__ unsigned int pk2n(float a, float b) {  // pack, no relu
  return (unsigned int)f2bf(a) | ((unsigned int)f2bf(b) << 16);
}

// ---------------- degree / CSR build ----------------
__global__ void k_cnt_init(int* __restrict__ cnt) {
  int i = blockIdx.x * 256 + threadIdx.x;
  if (i < NN) cnt[i] = 1;  // self-loop
}
__global__ void k_cnt(const int* __restrict__ dst, int* __restrict__ cnt) {
  int e = blockIdx.x * 256 + threadIdx.x;
  if (e < EE) atomicAdd(&cnt[dst[e]], 1);
}
__global__ void k_dis(const int* __restrict__ cnt, float* __restrict__ dis) {
  int i = blockIdx.x * 256 + threadIdx.x;
  if (i < NN) dis[i] = rsqrtf((float)cnt[i]);
}
__global__ __launch_bounds__(1024) void k_scan(const int* __restrict__ cnt,
                                               int* __restrict__ row_ptr,
                                               int* __restrict__ cur) {
  __shared__ int ls[1024];
  const int t = threadIdx.x;
  const int C = 49;  // 1024*49 >= NN
  int base = t * C;
  int s = 0;
  for (int i = 0; i < C; ++i) {
    int idx = base + i;
    if (idx < NN) s += cnt[idx] - 1;
  }
  ls[t] = s;
  __syncthreads();
  for (int off = 1; off < 1024; off <<= 1) {
    int v = (t >= off) ? ls[t - off] : 0;
    __syncthreads();
    ls[t] += v;
    __syncthreads();
  }
  int run = (t == 0) ? 0 : ls[t - 1];
  for (int i = 0; i < C; ++i) {
    int idx = base + i;
    if (idx < NN) {
      row_ptr[idx] = run;
      cur[idx] = run;
      run += cnt[idx] - 1;
    }
  }
}
__global__ void k_fill(const int* __restrict__ ei, const float* __restrict__ dis,
                       int* __restrict__ cur, int* __restrict__ col,
                       float* __restrict__ val) {
  int e = blockIdx.x * 256 + threadIdx.x;
  if (e >= EE) return;
  int s = ei[e], d = ei[EE + e];
  int pos = atomicAdd(&cur[d], 1);
  col[pos] = s;
  val[pos] = dis[s];
}

// ---------------- CSR gather aggregation: one wave per node ----------------
__global__ __launch_bounds__(256) void k_gather(const int* __restrict__ row_ptr,
                                                const int* __restrict__ cnt,
                                                const int* __restrict__ col,
                                                const float* __restrict__ val,
                                                const float* __restrict__ xw,
                                                const float* __restrict__ dis,
                                                float* __restrict__ x) {
  int node = blockIdx.x * 4 + (threadIdx.x >> 6);
  if (node >= NN) return;
  int l = threadIdx.x & 63;
  int c4 = l * 4;
  int beg = row_ptr[node];
  int num = cnt[node] - 1;
  float dv = dis[node];
  float4 a = ld4(&xw[(size_t)node * 256 + c4]);
  float4 acc = make_float4(a.x * dv, a.y * dv, a.z * dv, a.w * dv);
  int i = 0;
  for (; i + 2 <= num; i += 2) {
    int s0 = col[beg + i], s1 = col[beg + i + 1];
    float c0 = val[beg + i], c1 = val[beg + i + 1];
    float4 v0 = ld4(&xw[(size_t)s0 * 256 + c4]);
    float4 v1 = ld4(&xw[(size_t)s1 * 256 + c4]);
    acc.x += c0 * v0.x + c1 * v1.x;
    acc.y += c0 * v0.y + c1 * v1.y;
    acc.z += c0 * v0.z + c1 * v1.z;
    acc.w += c0 * v0.w + c1 * v1.w;
  }
  if (i < num) {
    int s0 = col[beg + i];
    float c0 = val[beg + i];
    float4 v0 = ld4(&xw[(size_t)s0 * 256 + c4]);
    acc.x += c0 * v0.x; acc.y += c0 * v0.y;
    acc.z += c0 * v0.z; acc.w += c0 * v0.w;
  }
  acc.x *= dv; acc.y *= dv; acc.z *= dv; acc.w *= dv;
  *(float4*)&x[(size_t)node * 256 + c4] = acc;
}

// ---------------- BatchNorm (training-mode) + ReLU ----------------
__global__ void k_bn_zero(float* __restrict__ s) {
  int i = blockIdx.x * 256 + threadIdx.x;
  if (i < 512) s[i] = 0.f;
}
__global__ void k_bn_stat(const float* __restrict__ x, float* __restrict__ sums) {
  int c = threadIdx.x;
  float s = 0.f, s2 = 0.f;
  for (int r = blockIdx.x; r < NN; r += gridDim.x) {
    float v = x[(size_t)r * HH + c];
    s += v; s2 += v * v;
  }
  atomicAdd(&sums[c], s);
  atomicAdd(&sums[HH + c], s2);
}
__global__ void k_bn_final(const float* __restrict__ sums, const float* __restrict__ gamma,
                           const float* __restrict__ beta, float* __restrict__ ss) {
  int c = threadIdx.x;
  float mu = sums[c] * (1.0f / NN);
  float var = sums[HH + c] * (1.0f / NN) - mu * mu;
  float s = gamma[c] * rsqrtf(var + EPSB);
  ss[c] = s;
  ss[HH + c] = beta[c] - mu * s;
}
__global__ void k_bn_apply(float* __restrict__ x, const float* __restrict__ ss) {
  int i = blockIdx.x * 256 + threadIdx.x;  // float4 index
  if (i < NN * 64) {
    int c4 = (i & 63) * 4;
    float4 sc = ld4(&ss[c4]);
    float4 sh = ld4(&ss[HH + c4]);
    float4 v = ld4(&x[(size_t)i * 4]);
    v.x = fmaxf(v.x * sc.x + sh.x, 0.f);
    v.y = fmaxf(v.y * sc.y + sh.y, 0.f);
    v.z = fmaxf(v.z * sc.z + sh.z, 0.f);
    v.w = fmaxf(v.w * sc.w + sh.w, 0.f);
    *(float4*)&x[(size_t)i * 4] = v;
  }
}

// ---------------- weight -> MFMA-fragment-linear bf16 packs ----------------
// W1f: B-operand frags for the P/Q GEMM, fusing the P|Q column permutation.
__global__ void k_w1frag(const float* __restrict__ W1, unsigned short* __restrict__ W1f) {
  int u = blockIdx.x * 256 + threadIdx.x;  // [0, 32768)
  int lane = u & 63, ks = (u >> 6) & 7, nt = u >> 9;
  int g = lane >> 4, li = lane & 15;
  int n = nt * 16 + li;
  size_t cadd = (n < 512) ? (size_t)n : (size_t)(n - 512) + 256 * 512;
  unsigned int wd[4];
#pragma unroll
  for (int jj = 0; jj < 4; ++jj) {
    int k0 = ks * 32 + g * 8 + jj * 2;
    float a = W1[(size_t)k0 * 512 + cadd];
    float b = W1[(size_t)(k0 + 1) * 512 + cadd];
    wd[jj] = pk2n(a, b);
  }
  *(uint4*)&W1f[(size_t)u * 8] = make_uint4(wd[0], wd[1], wd[2], wd[3]);
}
// W2f: A-operand frags for edge gemm2
__global__ void k_w2frag(const float* __restrict__ W2, unsigned short* __restrict__ W2f) {
  int u = blockIdx.x * 256 + threadIdx.x;  // [0, 16384)
  int lane = u & 63, ksg = (u >> 6) & 15, nt = u >> 10;
  int g = lane >> 4, li = lane & 15;
  unsigned int wd[4];
#pragma unroll
  for (int jj = 0; jj < 4; ++jj) {
    float a = W2[(size_t)(ksg * 32 + g * 8 + jj * 2) * 256 + nt * 16 + li];
    float b = W2[(size_t)(ksg * 32 + g * 8 + jj * 2 + 1) * 256 + nt * 16 + li];
    wd[jj] = pk2n(a, b);
  }
  *(uint4*)&W2f[(size_t)u * 8] = make_uint4(wd[0], wd[1], wd[2], wd[3]);
}
// W3f: A-operand frags for edge gemm3
__global__ void k_w3frag(const float* __restrict__ W3, unsigned short* __restrict__ W3f) {
  int u = blockIdx.x * 256 + threadIdx.x;  // [0, 4096)
  int lane = u & 63, ks = (u >> 6) & 7, mt = u >> 9;
  int g = lane >> 4, li = lane & 15;
  unsigned int wd[4];
#pragma unroll
  for (int jj = 0; jj < 4; ++jj) {
    float a = W3[(size_t)(ks * 32 + g * 8 + jj * 2) * 128 + mt * 16 + li];
    float b = W3[(size_t)(ks * 32 + g * 8 + jj * 2 + 1) * 128 + mt * 16 + li];
    wd[jj] = pk2n(a, b);
  }
  *(uint4*)&W3f[(size_t)u * 8] = make_uint4(wd[0], wd[1], wd[2], wd[3]);
}
// Wcf: B-operand frags for conv GEMM (one layer; N=256 -> nt in 0..15)
__global__ void k_wcfrag(const float* __restrict__ W, unsigned short* __restrict__ Wf) {
  int u = blockIdx.x * 256 + threadIdx.x;  // [0, 8192)
  int lane = u & 63, ks = (u >> 6) & 7, nt = u >> 9;
  int g = lane >> 4, li = lane & 15;
  unsigned int wd[4];
#pragma unroll
  for (int jj = 0; jj < 4; ++jj) {
    int k0 = ks * 32 + g * 8 + jj * 2;
    float a = W[(size_t)k0 * 256 + nt * 16 + li];
    float b = W[(size_t)(k0 + 1) * 256 + nt * 16 + li];
    wd[jj] = pk2n(a, b);
  }
  *(uint4*)&Wf[(size_t)u * 8] = make_uint4(wd[0], wd[1], wd[2], wd[3]);
}

// ---------------- conv GEMM via MFMA: xw[50000][256] = A @ convW_l, fp32 out
// Same structure as k_pq; fp32 float4 store via LDS round-trip.
__global__ __launch_bounds__(256, 2) void k_conv(const float* __restrict__ A,
                                                 const unsigned short* __restrict__ Wf,
                                                 float* __restrict__ C) {
  __shared__ uint4 ldsq[4096];  // 64 KB
  char* lds = (char*)ldsq;
  const int t = threadIdx.x;
  const int bm = blockIdx.x * 128;
  const int w = t >> 6, l = t & 63, g = l >> 4, li = l & 15;
  const int wm = w >> 1, wn = w & 1;

  {  // stage A[bm..+128][0..256] -> bf16 LDS, byte ^= (row&7)<<4
    int r = t >> 1, h = t & 1;
    int row = bm + r;
    int sw = (r & 7) << 4;
    const float* src = &A[(size_t)row * 256 + h * 128];
#pragma unroll
    for (int j = 0; j < 16; ++j) {
      float4 v0 = make_float4(0.f, 0.f, 0.f, 0.f), v1 = v0;
      if (row < NN) { v0 = ld4(src + j * 8); v1 = ld4(src + j * 8 + 4); }
      uint4 pk;
      pk.x = pk2n(v0.x, v0.y); pk.y = pk2n(v0.z, v0.w);
      pk.z = pk2n(v1.x, v1.y); pk.w = pk2n(v1.z, v1.w);
      *(uint4*)(lds + ((r * 512 + h * 256 + j * 16) ^ sw)) = pk;
    }
  }
  __syncthreads();

  f4v acc[4][4];
#pragma unroll
  for (int a = 0; a < 4; ++a)
#pragma unroll
    for (int b = 0; b < 4; ++b)
#pragma unroll
      for (int r = 0; r < 4; ++r) acc[a][b][r] = 0.f;

#pragma unroll
  for (int ks = 0; ks < 8; ++ks) {
    s8v af[4], bf[4];
#pragma unroll
    for (int a = 0; a < 4; ++a) {
      int row = wm * 64 + a * 16 + li;
      af[a] = *(const s8v*)(lds + ((row * 512 + ks * 64 + g * 16) ^ ((li & 7) << 4)));
    }
#pragma unroll
    for (int b = 0; b < 4; ++b) {
      int nt = blockIdx.y * 8 + wn * 4 + b;
      bf[b] = *(const s8v*)&Wf[(size_t)((nt * 8 + ks) * 64 + l) * 8];
    }
#pragma unroll
    for (int a = 0; a < 4; ++a)
#pragma unroll
      for (int b = 0; b < 4; ++b)
        acc[a][b] = __builtin_amdgcn_mfma_f32_16x16x32_bf16(af[a], bf[b], acc[a][b], 0, 0, 0);
  }
  __syncthreads();  // A dead; reuse LDS for C fp32 [128][128], swz by m

#pragma unroll
  for (int a = 0; a < 4; ++a)
#pragma unroll
    for (int b = 0; b < 4; ++b)
#pragma unroll
      for (int r = 0; r < 4; ++r) {
        int m = wm * 64 + a * 16 + g * 4 + r;
        int n = wn * 64 + b * 16 + li;
        *(float*)(lds + ((m * 512 + n * 4) ^ ((m & 7) << 4))) = acc[a][b][r];
      }
  __syncthreads();

  {  // coalesced fp32 store
    int r = t >> 1, h = t & 1;
    int row = bm + r;
    if (row < NN) {
      float* dst = &C[(size_t)row * 256 + blockIdx.y * 128 + h * 64];
      int sw = (r & 7) << 4;
#pragma unroll
      for (int j = 0; j < 8; ++j) {
        float4 v0 = *(const float4*)(lds + ((r * 512 + h * 256 + j * 32) ^ sw));
        float4 v1 = *(const float4*)(lds + ((r * 512 + h * 256 + j * 32 + 16) ^ sw));
        *(float4*)(dst + j * 8) = v0;
        *(float4*)(dst + j * 8 + 4) = v1;
      }
    }
  }
}

// ---------------- P/Q GEMM via MFMA: pqb[50000][1024] = x_buf @ w1r, bf16 out
__global__ __launch_bounds__(256, 2) void k_pq(const float* __restrict__ A,
                                               const unsigned short* __restrict__ W1f,
                                               unsigned short* __restrict__ C) {
  __shared__ uint4 ldsq[4096];  // 64 KB
  char* lds = (char*)ldsq;
  const int t = threadIdx.x;
  const int bm = blockIdx.x * 128;
  const int w = t >> 6, l = t & 63, g = l >> 4, li = l & 15;
  const int wm = w >> 1, wn = w & 1;

  {  // stage A -> bf16 LDS, byte ^= (row&7)<<4
    int r = t >> 1, h = t & 1;
    int row = bm + r;
    int sw = (r & 7) << 4;
    const float* src = &A[(size_t)row * 256 + h * 128];
#pragma unroll
    for (int j = 0; j < 16; ++j) {
      float4 v0 = make_float4(0.f, 0.f, 0.f, 0.f), v1 = v0;
      if (row < NN) { v0 = ld4(src + j * 8); v1 = ld4(src + j * 8 + 4); }
      uint4 pk;
      pk.x = pk2n(v0.x, v0.y); pk.y = pk2n(v0.z, v0.w);
      pk.z = pk2n(v1.x, v1.y); pk.w = pk2n(v1.z, v1.w);
      *(uint4*)(lds + ((r * 512 + h * 256 + j * 16) ^ sw)) = pk;
    }
  }
  __syncthreads();

  f4v acc[4][4];
#pragma unroll
  for (int a = 0; a < 4; ++a)
#pragma unroll
    for (int b = 0; b < 4; ++b)
#pragma unroll
      for (int r = 0; r < 4; ++r) acc[a][b][r] = 0.f;

#pragma unroll
  for (int ks = 0; ks < 8; ++ks) {
    s8v af[4], bf[4];
#pragma unroll
    for (int a = 0; a < 4; ++a) {
      int row = wm * 64 + a * 16 + li;
      af[a] = *(const s8v*)(lds + ((row * 512 + ks * 64 + g * 16) ^ ((li & 7) << 4)));
    }
#pragma unroll
    for (int b = 0; b < 4; ++b) {
      int nt = blockIdx.y * 8 + wn * 4 + b;
      bf[b] = *(const s8v*)&W1f[(size_t)((nt * 8 + ks) * 64 + l) * 8];
    }
#pragma unroll
    for (int a = 0; a < 4; ++a)
#pragma unroll
      for (int b = 0; b < 4; ++b)
        acc[a][b] = __builtin_amdgcn_mfma_f32_16x16x32_bf16(af[a], bf[b], acc[a][b], 0, 0, 0);
  }
  __syncthreads();  // reuse LDS for C fp32 [128][128], swz by m

#pragma unroll
  for (int a = 0; a < 4; ++a)
#pragma unroll
    for (int b = 0; b < 4; ++b)
#pragma unroll
      for (int r = 0; r < 4; ++r) {
        int m = wm * 64 + a * 16 + g * 4 + r;
        int n = wn * 64 + b * 16 + li;
        *(float*)(lds + ((m * 512 + n * 4) ^ ((m & 7) << 4))) = acc[a][b][r];
      }
  __syncthreads();

  {  // coalesced bf16 store
    int r = t >> 1, h = t & 1;
    int row = bm + r;
    if (row < NN) {
      unsigned short* dst = &C[(size_t)row * 1024 + blockIdx.y * 128 + h * 64];
      int sw = (r & 7) << 4;
#pragma unroll
      for (int j = 0; j < 8; ++j) {
        float4 v0 = *(const float4*)(lds + ((r * 512 + h * 256 + j * 32) ^ sw));
        float4 v1 = *(const float4*)(lds + ((r * 512 + h * 256 + j * 32 + 16) ^ sw));
        uint4 pk;
        pk.x = pk2n(v0.x, v0.y); pk.y = pk2n(v0.z, v0.w);
        pk.z = pk2n(v1.x, v1.y); pk.w = pk2n(v1.z, v1.w);
        *(uint4*)(dst + j * 8) = pk;
      }
    }
  }
}

// ---------------- fused edge MLP, MFMA: 64 edges/block, K-quartered h1 ----------------
// LDS 49.7 KB -> 3 blocks/CU (12 waves). red overlays h1 (dead after gemm2).
__global__ __launch_bounds__(256, 3) void k_edge(
    const int* __restrict__ ei, const unsigned short* __restrict__ pq,
    const float* __restrict__ b1, const unsigned short* __restrict__ W2f,
    const float* __restrict__ b2, const unsigned short* __restrict__ W3f,
    const float* __restrict__ b3, const float* __restrict__ W4,
    const float* __restrict__ b4, float* __restrict__ out) {
  __shared__ uint4 h1q[1024];       // 16 KB: h1 K-quarter [64 e][128 k] bf16 swz; later red[64][17]
  __shared__ uint4 h2q[2048];       // 32 KB: h2 [64 e][256 n] bf16 swz
  __shared__ int es[64], ed[64];
  char* h1b = (char*)h1q;
  char* h2b = (char*)h2q;
  float* red = (float*)h1q;         // [64][17], overlays h1
  const int t = threadIdx.x;
  const int e0 = blockIdx.x * 64;
  if (t < 64) {
    int e = e0 + t;
    es[t] = (e < EE) ? ei[e] : 0;
    ed[t] = (e < EE) ? ei[EE + e] : 0;
  }
  __syncthreads();

  const int w = t >> 6, l = t & 63, g = l >> 4, li = l & 15;
  const int eb = t >> 2, qq = t & 3;  // build roles: 4 threads/edge, 32 k each

  f4v acc2[4][4];
#pragma unroll
  for (int a = 0; a < 4; ++a)
#pragma unroll
    for (int b = 0; b < 4; ++b)
#pragma unroll
      for (int r = 0; r < 4; ++r) acc2[a][b][r] = 0.f;

  // ---- gemm2: [256 n][64 e] += W2t[n][512] x h1t[512][e], four K-quarters of 128
  for (int qt = 0; qt < 4; ++qt) {
    {  // build h1 quarter: relu(P[src]+Q[dst]+b1), bf16, XOR-swizzled by edge row
      size_t bp = (size_t)es[eb] * 1024 + qt * 128 + qq * 32;
      size_t bq = (size_t)ed[eb] * 1024 + 512 + qt * 128 + qq * 32;
      int sw = (eb & 7) << 4;
#pragma unroll
      for (int j = 0; j < 4; ++j) {
        uint4 pu = *(const uint4*)&pq[bp + j * 8];
        uint4 qu = *(const uint4*)&pq[bq + j * 8];
        const float* bb = &b1[qt * 128 + qq * 32 + j * 8];
        float4 c0 = ld4(bb), c1 = ld4(bb + 4);
        unsigned int r0 = pk2(bflo(pu.x) + bflo(qu.x) + c0.x, bfhi(pu.x) + bfhi(qu.x) + c0.y);
        unsigned int r1 = pk2(bflo(pu.y) + bflo(qu.y) + c0.z, bfhi(pu.y) + bfhi(qu.y) + c0.w);
        unsigned int r2 = pk2(bflo(pu.z) + bflo(qu.z) + c1.x, bfhi(pu.z) + bfhi(qu.z) + c1.y);
        unsigned int r3 = pk2(bflo(pu.w) + bflo(qu.w) + c1.z, bfhi(pu.w) + bfhi(qu.w) + c1.w);
        *(uint4*)(h1b + ((eb * 256 + qq * 64 + j * 16) ^ sw)) = make_uint4(r0, r1, r2, r3);
      }
    }
    __syncthreads();
#pragma unroll
    for (int kq = 0; kq < 4; ++kq) {
      int ksg = qt * 4 + kq;
      s8v af[4], bf[4];
#pragma unroll
      for (int a = 0; a < 4; ++a)
        af[a] = *(const s8v*)&W2f[(size_t)(((w * 4 + a) * 16 + ksg) * 64 + l) * 8];
#pragma unroll
      for (int b = 0; b < 4; ++b)
        bf[b] = *(const s8v*)(h1b + ((((b * 16 + li) * 256) + kq * 64 + g * 16) ^ ((li & 7) << 4)));
#pragma unroll
      for (int a = 0; a < 4; ++a)
#pragma unroll
        for (int b = 0; b < 4; ++b)
          acc2[a][b] = __builtin_amdgcn_mfma_f32_16x16x32_bf16(af[a], bf[b], acc2[a][b], 0, 0, 0);
    }
    __syncthreads();
  }

  // ---- h2[e][n] = bf16(relu(acc2 + b2[n])), swizzled by e
#pragma unroll
  for (int a = 0; a < 4; ++a) {
    int nb = w * 64 + a * 16 + g * 4;
    float4 bv = ld4(&b2[nb]);
#pragma unroll
    for (int b = 0; b < 4; ++b) {
      f4v v = acc2[a][b];
      uint2 pkd;
      pkd.x = pk2(v[0] + bv.x, v[1] + bv.y);
      pkd.y = pk2(v[2] + bv.z, v[3] + bv.w);
      *(uint2*)(h2b + ((((b * 16 + li) * 512) + nb * 2) ^ ((li & 7) << 4))) = pkd;
    }
  }
  __syncthreads();

  // ---- gemm3: [128 m][64 e] = W3t[m][256] x h2t[256][e]
  f4v acc3[2][4];
#pragma unroll
  for (int c = 0; c < 2; ++c)
#pragma unroll
    for (int b = 0; b < 4; ++b)
#pragma unroll
      for (int r = 0; r < 4; ++r) acc3[c][b][r] = 0.f;
#pragma unroll
  for (int ks = 0; ks < 8; ++ks) {
    s8v am[2], be[4];
#pragma unroll
    for (int c = 0; c < 2; ++c)
      am[c] = *(const s8v*)&W3f[(size_t)(((w * 2 + c) * 8 + ks) * 64 + l) * 8];
#pragma unroll
    for (int b = 0; b < 4; ++b)
      be[b] = *(const s8v*)(h2b + ((((b * 16 + li) * 512) + ks * 64 + g * 16) ^ ((li & 7) << 4)));
#pragma unroll
    for (int c = 0; c < 2; ++c)
#pragma unroll
      for (int b = 0; b < 4; ++b)
        acc3[c][b] = __builtin_amdgcn_mfma_f32_16x16x32_bf16(am[c], be[b], acc3[c][b], 0, 0, 0);
  }

  // ---- h3 relu + dot W4 -> red (overlaying h1; last h1 read was pre-barrier) -> out
  float part[4] = {0.f, 0.f, 0.f, 0.f};
#pragma unroll
  for (int c = 0; c < 2; ++c) {
    int mb = (w * 2 + c) * 16 + g * 4;
    float4 b3v = ld4(&b3[mb]);
    float4 w4v = ld4(&W4[mb]);
#pragma unroll
    for (int b = 0; b < 4; ++b) {
      f4v v = acc3[c][b];
      part[b] += fmaxf(v[0] + b3v.x, 0.f) * w4v.x + fmaxf(v[1] + b3v.y, 0.f) * w4v.y +
                 fmaxf(v[2] + b3v.z, 0.f) * w4v.z + fmaxf(v[3] + b3v.w, 0.f) * w4v.w;
    }
  }
#pragma unroll
  for (int b = 0; b < 4; ++b) red[(b * 16 + li) * 17 + w * 4 + g] = part[b];
  __syncthreads();
  if (t < 64) {
    float s = 0.f;
#pragma unroll
    for (int x = 0; x < 16; ++x) s += red[t * 17 + x];
    int e = e0 + t;
    if (e < EE) out[e] = s + b4[0];
  }
}

extern "C" void kernel_launch(void* const* d_in, const int* in_sizes, int n_in,
                              void* d_out, int out_size, void* d_ws, size_t ws_size,
                              hipStream_t stream) {
  const int* ei = (const int*)d_in[0];
  const float* node_emb = (const float*)d_in[1];
  const float* convW = (const float*)d_in[2];
  // d_in[3] = convB: cancels exactly in training-mode BN -> unused
  const float* bn_gamma = (const float*)d_in[4];
  const float* bn_beta = (const float*)d_in[5];
  const float* W1 = (const float*)d_in[6];
  const float* b1 = (const float*)d_in[7];
  const float* W2 = (const float*)d_in[8];
  const float* b2 = (const float*)d_in[9];
  const float* W3 = (const float*)d_in[10];
  const float* b3 = (const float*)d_in[11];
  const float* W4 = (const float*)d_in[12];
  const float* b4 = (const float*)d_in[13];
  float* out = (float*)d_out;

  char* w = (char*)d_ws;
  float* x_buf = (float*)w;             w += 51200000;   // [50000][256] fp32
  char* uni = w;                        w += 102400000;  // union region
  float* xw = (float*)uni;                               // [50000][256] fp32 (layers)
  unsigned short* pqb = (unsigned short*)uni;            // [50000][1024] bf16 (P|Q)
  unsigned short* W1f = (unsigned short*)w; w += 524288;  // frag-linear bf16 W1 (P|Q fused)
  float* dis   = (float*)w; w += 200704;     // [50000]
  int*   cnt   = (int*)w;   w += 200704;     // [50000]
  float* bnsum = (float*)w; w += 4096;       // [512]
  float* bnss  = (float*)w; w += 4096;       // [512]
  unsigned short* W2f = (unsigned short*)w; w += 262144;  // frag-linear bf16 W2
  unsigned short* W3f = (unsigned short*)w; w += 65536;   // frag-linear bf16 W3
  unsigned short* Wcf = (unsigned short*)w; w += 262144;  // frag-linear bf16 convW (2 layers)
  int*   row_ptr = (int*)w; w += 200704;     // [50000]
  int*   curp    = (int*)w; w += 200704;     // [50000]
  int*   colv    = (int*)w; w += 2000896;    // [500000]
  float* valv    = (float*)w; w += 2000896;  // [500000]
  (void)ws_size; (void)in_sizes; (void)n_in; (void)out_size;

  // CSR build + weight fragment packs
  k_cnt_init<<<196, 256, 0, stream>>>(cnt);
  k_cnt<<<(EE + 255) / 256, 256, 0, stream>>>(ei + EE, cnt);
  k_dis<<<196, 256, 0, stream>>>(cnt, dis);
  k_scan<<<1, 1024, 0, stream>>>(cnt, row_ptr, curp);
  k_fill<<<(EE + 255) / 256, 256, 0, stream>>>(ei, dis, curp, colv, valv);
  k_w1frag<<<128, 256, 0, stream>>>(W1, W1f);
  k_w2frag<<<64, 256, 0, stream>>>(W2, W2f);
  k_w3frag<<<16, 256, 0, stream>>>(W3, W3f);
  k_wcfrag<<<32, 256, 0, stream>>>(convW, Wcf);
  k_wcfrag<<<32, 256, 0, stream>>>(convW + 65536, Wcf + 65536);

  for (int l = 0; l < 2; ++l) {
    const float* A = (l == 0) ? node_emb : x_buf;
    k_conv<<<dim3(391, 2), 256, 0, stream>>>(A, Wcf + l * 65536, xw);
    k_gather<<<12500, 256, 0, stream>>>(row_ptr, cnt, colv, valv, xw, dis, x_buf);
    k_bn_zero<<<2, 256, 0, stream>>>(bnsum);
    k_bn_stat<<<512, 256, 0, stream>>>(x_buf, bnsum);
    k_bn_final<<<1, 256, 0, stream>>>(bnsum, bn_gamma + l * HH, bn_beta + l * HH, bnss);
    k_bn_apply<<<12500, 256, 0, stream>>>(x_buf, bnss);
  }

  k_pq<<<dim3(391, 8), 256, 0, stream>>>(x_buf, W1f, pqb);
  k_edge<<<7813, 256, 0, stream>>>(ei, pqb, b1, W2f, b2, W3f, b3, W4, b4, out);
}